// Round 2
// baseline (733.779 us; speedup 1.0000x reference)
//
#include <hip/hip_runtime.h>
#include <hip/hip_bf16.h>
#include <math.h>

#define NAn 40000
#define NBn 40000
#define NEe 250000
#define Cc 128
#define Hh 4
#define Ll 2
static constexpr float INV_SQRT_D = 0.17677669529663687f; // 1/sqrt(32)

typedef __hip_bfloat16 bf16;
typedef unsigned short u16;
typedef unsigned int u32;

__device__ __forceinline__ float bf2f(bf16 x) { return __bfloat162float(x); }
__device__ __forceinline__ float lo_bf(u32 w) { return __uint_as_float(w << 16); }
__device__ __forceinline__ float hi_bf(u32 w) { return __uint_as_float(w & 0xffff0000u); }

// adaptive scalar load: isb=1 -> bf16, else f32
__device__ __forceinline__ float ldf(const void* p, size_t i, int isb) {
    return isb ? bf2f(((const bf16*)p)[i]) : ((const float*)p)[i];
}

// ---------------- dtype detection ----------------
// Interpret first n u16s of x as bf16. If data is really f32, the low halves
// of floats reinterpret to bf16 values with random exponents -> max >> 1e4.
__global__ void k_detect(const u16* __restrict__ x, int n, int* __restrict__ flag) {
    __shared__ float smax[256];
    int tid = threadIdx.x;
    float m = 0.f;
    for (int i = tid; i < n; i += 256) {
        float v = fabsf(__uint_as_float(((u32)x[i]) << 16));
        if (v != v) v = 1e30f;
        m = fmaxf(m, v);
    }
    smax[tid] = m;
    __syncthreads();
    for (int s = 128; s > 0; s >>= 1) {
        if (tid < s) smax[tid] = fmaxf(smax[tid], smax[tid + s]);
        __syncthreads();
    }
    if (tid == 0) flag[0] = (smax[0] > 1e4f) ? 0 : 1;
}

// ---------------- small converts (adaptive) ----------------
__global__ void k_convert(const void* __restrict__ src, float* __restrict__ dst, int n,
                          const int* __restrict__ dflag) {
    int isb = dflag[0];
    int i = blockIdx.x * blockDim.x + threadIdx.x;
    if (i < n) dst[i] = ldf(src, i, isb);
}

// ---------------- fused KQV weight prep ----------------
// W[lt][c][j]: j<128: k' = sum_d k_w[lt,c,h*32+d]*a_rel[lt,h,d,e]*(p_rel[lt,h]*INV_SQRT_D)
//              128<=j<256: q_w ; j>=256: v' with m_rel
__global__ void k_prep_kqv_w(const void* __restrict__ k_w, const void* __restrict__ q_w,
                             const void* __restrict__ v_w, const void* __restrict__ a_rel,
                             const void* __restrict__ m_rel, const void* __restrict__ p_rel,
                             float* __restrict__ W, const int* __restrict__ dflag) {
    int isb = dflag[0];
    int b = blockIdx.x;          // lt*128 + c
    int lt = b >> 7, c = b & 127;
    int j = threadIdx.x;         // 0..383
    float out;
    if (j < 128) {
        int h = j >> 5, e = j & 31;
        float s = ldf(p_rel, lt * Hh + h, isb) * INV_SQRT_D;
        float sum = 0.f;
        size_t kw0 = ((size_t)lt * 128 + c) * 128 + h * 32;
        size_t ar0 = ((size_t)lt * Hh + h) * 1024 + e;
        #pragma unroll
        for (int d = 0; d < 32; ++d) sum += ldf(k_w, kw0 + d, isb) * ldf(a_rel, ar0 + d * 32, isb);
        out = sum * s;
    } else if (j < 256) {
        out = ldf(q_w, ((size_t)lt * 128 + c) * 128 + (j - 128), isb);
    } else {
        int jj = j - 256;
        int h = jj >> 5, e = jj & 31;
        float sum = 0.f;
        size_t vw0 = ((size_t)lt * 128 + c) * 128 + h * 32;
        size_t mr0 = ((size_t)lt * Hh + h) * 1024 + e;
        #pragma unroll
        for (int d = 0; d < 32; ++d) sum += ldf(v_w, vw0 + d, isb) * ldf(m_rel, mr0 + d * 32, isb);
        out = sum;
    }
    W[((size_t)lt * 128 + c) * 384 + j] = out;
}

__global__ void k_prep_kqv_b(const void* __restrict__ k_b, const void* __restrict__ q_b,
                             const void* __restrict__ v_b, const void* __restrict__ a_rel,
                             const void* __restrict__ m_rel, const void* __restrict__ p_rel,
                             float* __restrict__ B, const int* __restrict__ dflag) {
    int isb = dflag[0];
    int lt = blockIdx.x;
    int j = threadIdx.x;
    float out;
    if (j < 128) {
        int h = j >> 5, e = j & 31;
        float s = ldf(p_rel, lt * Hh + h, isb) * INV_SQRT_D;
        float sum = 0.f;
        size_t kb0 = (size_t)lt * 128 + h * 32;
        size_t ar0 = ((size_t)lt * Hh + h) * 1024 + e;
        #pragma unroll
        for (int d = 0; d < 32; ++d) sum += ldf(k_b, kb0 + d, isb) * ldf(a_rel, ar0 + d * 32, isb);
        out = sum * s;
    } else if (j < 256) {
        out = ldf(q_b, (size_t)lt * 128 + (j - 128), isb);
    } else {
        int jj = j - 256;
        int h = jj >> 5, e = jj & 31;
        float sum = 0.f;
        size_t vb0 = (size_t)lt * 128 + h * 32;
        size_t mr0 = ((size_t)lt * Hh + h) * 1024 + e;
        #pragma unroll
        for (int d = 0; d < 32; ++d) sum += ldf(v_b, vb0 + d, isb) * ldf(m_rel, mr0 + d * 32, isb);
        out = sum;
    }
    B[(size_t)lt * 384 + j] = out;
}

// ---------------- CSR build ----------------
__global__ void k_hist(const int* __restrict__ dst, int* __restrict__ deg, int ne) {
    int i = blockIdx.x * blockDim.x + threadIdx.x;
    if (i < ne) atomicAdd(&deg[dst[i]], 1);
}

__global__ void k_scanA(const int* __restrict__ deg, int* __restrict__ excl,
                        int* __restrict__ bsum, int n) {
    __shared__ int buf[256];
    int tid = threadIdx.x;
    int i = blockIdx.x * 256 + tid;
    int v = (i < n) ? deg[i] : 0;
    buf[tid] = v;
    __syncthreads();
    for (int off = 1; off < 256; off <<= 1) {
        int u = (tid >= off) ? buf[tid - off] : 0;
        __syncthreads();
        buf[tid] += u;
        __syncthreads();
    }
    int incl = buf[tid];
    if (i < n) excl[i] = incl - v;
    if (tid == 255) bsum[blockIdx.x] = incl;
}

__global__ void k_scanB(int* __restrict__ bsum, int nb) {
    __shared__ int buf[256];
    int tid = threadIdx.x;
    int v = (tid < nb) ? bsum[tid] : 0;
    buf[tid] = v;
    __syncthreads();
    for (int off = 1; off < 256; off <<= 1) {
        int u = (tid >= off) ? buf[tid - off] : 0;
        __syncthreads();
        buf[tid] += u;
        __syncthreads();
    }
    if (tid < nb) bsum[tid] = buf[tid] - v; // exclusive over blocks
}

__global__ void k_scanC(int* __restrict__ rowptr, const int* __restrict__ bsum, int n, int total) {
    int i = blockIdx.x * 256 + threadIdx.x;
    if (i < n) rowptr[i] += bsum[i >> 8];
    if (i == 0) rowptr[n] = total;
}

__global__ void k_scatter(const int* __restrict__ src, const int* __restrict__ dst,
                          int* __restrict__ cursor, int* __restrict__ csr_src, int ne) {
    int i = blockIdx.x * blockDim.x + threadIdx.x;
    if (i < ne) {
        int d = dst[i];
        int p = atomicAdd(&cursor[d], 1);
        csr_src[p] = src[i];
    }
}

// ---------------- GEMM: out[M,N] = epi(act(A[M,K]) @ W[K,Ntot] + bias) ----------------
// AMODE: 0 = A is f32, 1 = A is bf16, 2 = adaptive (dflag)
// EPI:   0 = +bias ; 1 = relu ; 2 = skip blend s*(acc+bias)+(1-s)*oldx
// OMODE: 0 = f32 out, 1 = bf16 out
template <int AMODE, bool GELU, int EPI, int OMODE>
__global__ __launch_bounds__(256) void k_gemm(const void* __restrict__ A, int lda,
                                              const float* __restrict__ W,
                                              const float* __restrict__ bias,
                                              void* __restrict__ out, int ldo,
                                              int M, int K, int N,
                                              const float* __restrict__ oldx,
                                              const void* __restrict__ skipp, int skip_idx,
                                              const int* __restrict__ dflag) {
    __shared__ float As[64][33];
    __shared__ float Bs[32][128];
    int isb = (AMODE == 2) ? dflag[0] : (AMODE == 1);
    int tid = threadIdx.x;
    int r0 = blockIdx.x * 64;
    int n0 = blockIdx.y * 128;
    int ty = tid >> 4, tx = tid & 15;
    float acc[4][8] = {};
    for (int k0 = 0; k0 < K; k0 += 32) {
        #pragma unroll
        for (int i = 0; i < 8; ++i) {
            int idx = tid + i * 256;
            int r = idx >> 5, c = idx & 31;
            float v = ldf(A, (size_t)(r0 + r) * lda + k0 + c, isb);
            if (GELU) v = 0.5f * v * (1.f + erff(v * 0.70710678118f));
            As[r][c] = v;
        }
        #pragma unroll
        for (int i = 0; i < 16; ++i) {
            int idx = tid + i * 256;
            int c = idx >> 7, j = idx & 127;
            Bs[c][j] = W[(size_t)(k0 + c) * N + n0 + j];
        }
        __syncthreads();
        #pragma unroll
        for (int c = 0; c < 32; ++c) {
            float aa[4];
            #pragma unroll
            for (int i = 0; i < 4; ++i) aa[i] = As[ty * 4 + i][c];
            float4 b0 = *(const float4*)&Bs[c][tx * 8];
            float4 b1 = *(const float4*)&Bs[c][tx * 8 + 4];
            float bb[8] = {b0.x, b0.y, b0.z, b0.w, b1.x, b1.y, b1.z, b1.w};
            #pragma unroll
            for (int i = 0; i < 4; ++i)
                #pragma unroll
                for (int j = 0; j < 8; ++j) acc[i][j] += aa[i] * bb[j];
        }
        __syncthreads();
    }
    float s = 0.f;
    if (EPI == 2) {
        float sv = ldf(skipp, skip_idx, (AMODE == 2) ? isb : dflag[0]);
        s = 1.f / (1.f + expf(-sv));
    }
    #pragma unroll
    for (int i = 0; i < 4; ++i) {
        int gr = r0 + ty * 4 + i;
        #pragma unroll
        for (int j = 0; j < 8; ++j) {
            int gc = n0 + tx * 8 + j;
            float o = acc[i][j] + bias[gc];
            if (EPI == 1) o = fmaxf(o, 0.f);
            if (EPI == 2) o = s * o + (1.f - s) * oldx[(size_t)gr * 128 + gc];
            if (OMODE == 0) ((float*)out)[(size_t)gr * ldo + gc] = o;
            else            ((bf16*)out)[(size_t)gr * ldo + gc] = __float2bfloat16(o);
        }
    }
}

// ---------------- edge aggregation (softmax message passing) ----------------
// kv: src-side kqv bf16 [Nsrc][384] (cols 0..127 scaled k', 256..383 v')
// qm: dst-side kqv bf16 [Ndst][384] (cols 128..255 = q). Output overwrites qm's
// q-columns (each wave reads its own q before writing its own row -> safe).
__global__ __launch_bounds__(256) void k_edge(const bf16* __restrict__ kv, bf16* __restrict__ qm,
                                              const int* __restrict__ rowptr,
                                              const int* __restrict__ csr_src, int n_dst) {
    int wave = threadIdx.x >> 6, lane = threadIdx.x & 63;
    int n = blockIdx.x * 4 + wave;
    if (n >= n_dst) return;
    int h = lane >> 4, j = lane & 15;
    int col = h * 32 + j * 2;
    bf16* qp = qm + (size_t)n * 384 + 128 + col;
    u32 qw = *(const u32*)qp;
    float qx = lo_bf(qw), qy = hi_bf(qw);
    float ax = 0.f, ay = 0.f, den = 0.f;
    int e0 = rowptr[n], e1 = rowptr[n + 1];
    for (int e = e0; e < e1; ++e) {
        int sidx = csr_src[e];
        const bf16* base = kv + (size_t)sidx * 384;
        u32 kw = *(const u32*)(base + col);
        float part = qx * lo_bf(kw) + qy * hi_bf(kw);
        part += __shfl_xor(part, 1);
        part += __shfl_xor(part, 2);
        part += __shfl_xor(part, 4);
        part += __shfl_xor(part, 8);
        float w = expf(part);
        u32 vw = *(const u32*)(base + 256 + col);
        den += w;
        ax += w * lo_bf(vw);
        ay += w * hi_bf(vw);
    }
    float inv = 1.f / (den + 1e-16f);
    union { bf16 h2[2]; u32 u; } pk;
    pk.h2[0] = __float2bfloat16(ax * inv);
    pk.h2[1] = __float2bfloat16(ay * inv);
    *(u32*)qp = pk.u;
}

// ---------------- final output (adaptive dtype) ----------------
__global__ void k_out(const float* __restrict__ xa, const float* __restrict__ xb,
                      void* __restrict__ out, int n_each, const int* __restrict__ dflag) {
    int isb = dflag[0];
    int i = blockIdx.x * blockDim.x + threadIdx.x;
    if (i >= 2 * n_each) return;
    float v = (i < n_each) ? xa[i] : xb[i - n_each];
    if (isb) ((bf16*)out)[i] = __float2bfloat16(v);
    else     ((float*)out)[i] = v;
}

extern "C" void kernel_launch(void* const* d_in, const int* in_sizes, int n_in,
                              void* d_out, int out_size, void* d_ws, size_t ws_size,
                              hipStream_t stream) {
    const void* x_a     = d_in[0];
    const void* x_b     = d_in[1];
    const int*  edge_ab = (const int*)d_in[2];
    const int*  edge_ba = (const int*)d_in[3];
    const void* lin_a_w = d_in[4];
    const void* lin_a_b = d_in[5];
    const void* lin_b_w = d_in[6];
    const void* lin_b_b = d_in[7];
    const void* k_w     = d_in[8];
    const void* k_b     = d_in[9];
    const void* q_w     = d_in[10];
    const void* q_b     = d_in[11];
    const void* v_w     = d_in[12];
    const void* v_b     = d_in[13];
    const void* a_rel   = d_in[14];
    const void* m_rel   = d_in[15];
    const void* p_rel   = d_in[16];
    const void* a_lin_w = d_in[17];
    const void* a_lin_b = d_in[18];
    const void* skip    = d_in[19];

    // -------- workspace layout: f32 block, then bf16 block, then int block --------
    char* p = (char*)d_ws;
    auto falloc = [&](size_t n) { float* r = (float*)p; p += n * sizeof(float); return r; };
    float* xa      = falloc((size_t)NAn * Cc);
    float* xb      = falloc((size_t)NBn * Cc);
    float* w_lin_a = falloc(64 * 128);
    float* b_lin_a = falloc(128);
    float* w_lin_b = falloc(32 * 128);
    float* b_lin_b = falloc(128);
    float* w_kqv   = falloc(4 * 128 * 384);
    float* b_kqv   = falloc(4 * 384);
    float* w_alin  = falloc(4 * 128 * 128);
    float* b_alin  = falloc(4 * 128);
    auto halloc = [&](size_t n) { bf16* r = (bf16*)p; p += n * sizeof(bf16); return r; };
    bf16* kqv_a = halloc((size_t)NAn * 384);
    bf16* kqv_b = halloc((size_t)NBn * 384);
    auto ialloc = [&](size_t n) { int* r = (int*)p; p += n * sizeof(int); return r; };
    int* dflag     = ialloc(4);
    int* rowptr_ab = ialloc(NBn + 1);
    int* rowptr_ba = ialloc(NAn + 1);
    int* deg_ab    = ialloc(NBn);
    int* deg_ba    = ialloc(NAn);
    int* cursor_ab = ialloc(NBn);
    int* cursor_ba = ialloc(NAn);
    int* bsum_ab   = ialloc(256);
    int* bsum_ba   = ialloc(256);
    int* csr_ab    = ialloc(NEe);
    int* csr_ba    = ialloc(NEe);

    // -------- dtype detection (must run first) --------
    k_detect<<<1, 256, 0, stream>>>((const u16*)x_a, 8192, dflag);

    // -------- weight prep --------
    k_convert<<<(64 * 128 + 255) / 256, 256, 0, stream>>>(lin_a_w, w_lin_a, 64 * 128, dflag);
    k_convert<<<1, 128, 0, stream>>>(lin_a_b, b_lin_a, 128, dflag);
    k_convert<<<(32 * 128 + 255) / 256, 256, 0, stream>>>(lin_b_w, w_lin_b, 32 * 128, dflag);
    k_convert<<<1, 128, 0, stream>>>(lin_b_b, b_lin_b, 128, dflag);
    k_convert<<<(4 * 128 * 128 + 255) / 256, 256, 0, stream>>>(a_lin_w, w_alin, 4 * 128 * 128, dflag);
    k_convert<<<2, 256, 0, stream>>>(a_lin_b, b_alin, 512, dflag);
    k_prep_kqv_w<<<512, 384, 0, stream>>>(k_w, q_w, v_w, a_rel, m_rel, p_rel, w_kqv, dflag);
    k_prep_kqv_b<<<4, 384, 0, stream>>>(k_b, q_b, v_b, a_rel, m_rel, p_rel, b_kqv, dflag);

    // -------- CSR build (group by dst) --------
    hipMemsetAsync(deg_ab, 0, NBn * sizeof(int), stream);
    hipMemsetAsync(deg_ba, 0, NAn * sizeof(int), stream);
    k_hist<<<(NEe + 255) / 256, 256, 0, stream>>>(edge_ab + NEe, deg_ab, NEe);
    k_hist<<<(NEe + 255) / 256, 256, 0, stream>>>(edge_ba + NEe, deg_ba, NEe);
    int nblk = (NBn + 255) / 256; // 157
    k_scanA<<<nblk, 256, 0, stream>>>(deg_ab, rowptr_ab, bsum_ab, NBn);
    k_scanA<<<nblk, 256, 0, stream>>>(deg_ba, rowptr_ba, bsum_ba, NAn);
    k_scanB<<<1, 256, 0, stream>>>(bsum_ab, nblk);
    k_scanB<<<1, 256, 0, stream>>>(bsum_ba, nblk);
    k_scanC<<<nblk, 256, 0, stream>>>(rowptr_ab, bsum_ab, NBn, NEe);
    k_scanC<<<nblk, 256, 0, stream>>>(rowptr_ba, bsum_ba, NAn, NEe);
    hipMemcpyAsync(cursor_ab, rowptr_ab, NBn * sizeof(int), hipMemcpyDeviceToDevice, stream);
    hipMemcpyAsync(cursor_ba, rowptr_ba, NAn * sizeof(int), hipMemcpyDeviceToDevice, stream);
    k_scatter<<<(NEe + 255) / 256, 256, 0, stream>>>(edge_ab, edge_ab + NEe, cursor_ab, csr_ab, NEe);
    k_scatter<<<(NEe + 255) / 256, 256, 0, stream>>>(edge_ba, edge_ba + NEe, cursor_ba, csr_ba, NEe);

    // -------- input linears + relu (adaptive A dtype) --------
    k_gemm<2, false, 1, 0><<<dim3(NAn / 64, 1), 256, 0, stream>>>(
        x_a, 64, w_lin_a, b_lin_a, xa, 128, NAn, 64, 128, nullptr, nullptr, 0, dflag);
    k_gemm<2, false, 1, 0><<<dim3(NBn / 64, 1), 256, 0, stream>>>(
        x_b, 32, w_lin_b, b_lin_b, xb, 128, NBn, 32, 128, nullptr, nullptr, 0, dflag);

    // -------- layers --------
    for (int l = 0; l < Ll; ++l) {
        int lt0 = l * 2 + 0, lt1 = l * 2 + 1;
        // fused k'/q/v' projections -> bf16 kqv buffers
        k_gemm<0, false, 0, 1><<<dim3(NAn / 64, 3), 256, 0, stream>>>(
            xa, 128, w_kqv + (size_t)lt0 * 128 * 384, b_kqv + (size_t)lt0 * 384,
            kqv_a, 384, NAn, 128, 384, nullptr, nullptr, 0, dflag);
        k_gemm<0, false, 0, 1><<<dim3(NBn / 64, 3), 256, 0, stream>>>(
            xb, 128, w_kqv + (size_t)lt1 * 128 * 384, b_kqv + (size_t)lt1 * 384,
            kqv_b, 384, NBn, 128, 384, nullptr, nullptr, 0, dflag);
        // edge AB: k/v from A, q from B -> writes attn_b into kqv_b q-cols
        k_edge<<<(NBn + 3) / 4, 256, 0, stream>>>(kqv_a, kqv_b, rowptr_ab, csr_ab, NBn);
        // edge BA: k/v from B, q from A -> writes attn_a into kqv_a q-cols
        k_edge<<<(NAn + 3) / 4, 256, 0, stream>>>(kqv_b, kqv_a, rowptr_ba, csr_ba, NAn);
        // a_lin(gelu(attn)) + sigmoid-skip blend, in-place update of xa/xb (f32)
        k_gemm<1, true, 2, 0><<<dim3(NAn / 64, 1), 256, 0, stream>>>(
            kqv_a + 128, 384, w_alin + (size_t)lt0 * 128 * 128, b_alin + (size_t)lt0 * 128,
            xa, 128, NAn, 128, 128, xa, skip, lt0, dflag);
        k_gemm<1, true, 2, 0><<<dim3(NBn / 64, 1), 256, 0, stream>>>(
            kqv_b + 128, 384, w_alin + (size_t)lt1 * 128 * 128, b_alin + (size_t)lt1 * 128,
            xb, 128, NBn, 128, 128, xb, skip, lt1, dflag);
    }

    // -------- output --------
    int n_each = NAn * Cc;
    k_out<<<(2 * n_each + 255) / 256, 256, 0, stream>>>(xa, xb, d_out, n_each, dflag);
}

// Round 3
// 472.758 us; speedup vs baseline: 1.5521x; 1.5521x over previous
//
#include <hip/hip_runtime.h>
#include <hip/hip_bf16.h>
#include <math.h>

#define NAn 40000
#define NBn 40000
#define NEe 250000
#define Cc 128
#define Hh 4
#define Ll 2
static constexpr float INV_SQRT_D = 0.17677669529663687f; // 1/sqrt(32)

typedef __hip_bfloat16 bf16;
typedef unsigned short u16;
typedef unsigned int u32;
typedef short s16x8 __attribute__((ext_vector_type(8)));
typedef float f32x4 __attribute__((ext_vector_type(4)));

__device__ __forceinline__ float bf2f(bf16 x) { return __bfloat162float(x); }
__device__ __forceinline__ float lo_bf(u32 w) { return __uint_as_float(w << 16); }
__device__ __forceinline__ float hi_bf(u32 w) { return __uint_as_float(w & 0xffff0000u); }

// adaptive scalar load: isb=1 -> bf16, else f32
__device__ __forceinline__ float ldf(const void* p, size_t i, int isb) {
    return isb ? bf2f(((const bf16*)p)[i]) : ((const float*)p)[i];
}

__device__ __forceinline__ u16 f2bu(float v) {
    union { bf16 b; u16 u; } c; c.b = __float2bfloat16(v); return c.u;
}

// ---------------- dtype detection ----------------
__global__ void k_detect(const u16* __restrict__ x, int n, int* __restrict__ flag) {
    __shared__ float smax[256];
    int tid = threadIdx.x;
    float m = 0.f;
    for (int i = tid; i < n; i += 256) {
        float v = fabsf(__uint_as_float(((u32)x[i]) << 16));
        if (v != v) v = 1e30f;
        m = fmaxf(m, v);
    }
    smax[tid] = m;
    __syncthreads();
    for (int s = 128; s > 0; s >>= 1) {
        if (tid < s) smax[tid] = fmaxf(smax[tid], smax[tid + s]);
        __syncthreads();
    }
    if (tid == 0) flag[0] = (smax[0] > 1e4f) ? 0 : 1;
}

// ---------------- converts ----------------
__global__ void k_convert(const void* __restrict__ src, float* __restrict__ dst, int n,
                          const int* __restrict__ dflag) {
    int isb = dflag[0];
    int i = blockIdx.x * blockDim.x + threadIdx.x;
    if (i < n) dst[i] = ldf(src, i, isb);
}

__global__ void k_convb(const void* __restrict__ src, bf16* __restrict__ dst, int n,
                        const int* __restrict__ dflag) {
    int isb = dflag[0];
    int i = blockIdx.x * blockDim.x + threadIdx.x;
    if (i < n) dst[i] = isb ? ((const bf16*)src)[i] : __float2bfloat16(((const float*)src)[i]);
}

// transpose slice: src[slice][K][N] -> dst[slice][N][K] bf16 (adaptive src dtype)
__global__ void k_tw(const void* __restrict__ src, bf16* __restrict__ dst, int K, int N,
                     const int* __restrict__ dflag) {
    int isb = dflag[0];
    int slice = blockIdx.y;
    int idx = blockIdx.x * 256 + threadIdx.x; // = n*K + k
    if (idx >= K * N) return;
    int n = idx / K, k = idx - n * K;
    float v = ldf(src, (size_t)slice * K * N + (size_t)k * N + n, isb);
    dst[(size_t)slice * K * N + idx] = __float2bfloat16(v);
}

// ---------------- fused KQV weight prep (writes TRANSPOSED Wt[lt][384][128] bf16) ----------------
__global__ void k_prep_kqv_w(const void* __restrict__ k_w, const void* __restrict__ q_w,
                             const void* __restrict__ v_w, const void* __restrict__ a_rel,
                             const void* __restrict__ m_rel, const void* __restrict__ p_rel,
                             bf16* __restrict__ Wt, const int* __restrict__ dflag) {
    int isb = dflag[0];
    int b = blockIdx.x;          // lt*128 + c  (c = K index)
    int lt = b >> 7, c = b & 127;
    int j = threadIdx.x;         // 0..383 (N index)
    float out;
    if (j < 128) {
        int h = j >> 5, e = j & 31;
        float s = ldf(p_rel, lt * Hh + h, isb) * INV_SQRT_D;
        float sum = 0.f;
        size_t kw0 = ((size_t)lt * 128 + c) * 128 + h * 32;
        size_t ar0 = ((size_t)lt * Hh + h) * 1024 + e;
        #pragma unroll
        for (int d = 0; d < 32; ++d) sum += ldf(k_w, kw0 + d, isb) * ldf(a_rel, ar0 + d * 32, isb);
        out = sum * s;
    } else if (j < 256) {
        out = ldf(q_w, ((size_t)lt * 128 + c) * 128 + (j - 128), isb);
    } else {
        int jj = j - 256;
        int h = jj >> 5, e = jj & 31;
        float sum = 0.f;
        size_t vw0 = ((size_t)lt * 128 + c) * 128 + h * 32;
        size_t mr0 = ((size_t)lt * Hh + h) * 1024 + e;
        #pragma unroll
        for (int d = 0; d < 32; ++d) sum += ldf(v_w, vw0 + d, isb) * ldf(m_rel, mr0 + d * 32, isb);
        out = sum;
    }
    Wt[((size_t)lt * 384 + j) * 128 + c] = __float2bfloat16(out);
}

__global__ void k_prep_kqv_b(const void* __restrict__ k_b, const void* __restrict__ q_b,
                             const void* __restrict__ v_b, const void* __restrict__ a_rel,
                             const void* __restrict__ m_rel, const void* __restrict__ p_rel,
                             float* __restrict__ B, const int* __restrict__ dflag) {
    int isb = dflag[0];
    int lt = blockIdx.x;
    int j = threadIdx.x;
    float out;
    if (j < 128) {
        int h = j >> 5, e = j & 31;
        float s = ldf(p_rel, lt * Hh + h, isb) * INV_SQRT_D;
        float sum = 0.f;
        size_t kb0 = (size_t)lt * 128 + h * 32;
        size_t ar0 = ((size_t)lt * Hh + h) * 1024 + e;
        #pragma unroll
        for (int d = 0; d < 32; ++d) sum += ldf(k_b, kb0 + d, isb) * ldf(a_rel, ar0 + d * 32, isb);
        out = sum * s;
    } else if (j < 256) {
        out = ldf(q_b, (size_t)lt * 128 + (j - 128), isb);
    } else {
        int jj = j - 256;
        int h = jj >> 5, e = jj & 31;
        float sum = 0.f;
        size_t vb0 = (size_t)lt * 128 + h * 32;
        size_t mr0 = ((size_t)lt * Hh + h) * 1024 + e;
        #pragma unroll
        for (int d = 0; d < 32; ++d) sum += ldf(v_b, vb0 + d, isb) * ldf(m_rel, mr0 + d * 32, isb);
        out = sum;
    }
    B[(size_t)lt * 384 + j] = out;
}

// ---------------- CSR build ----------------
__global__ void k_hist(const int* __restrict__ dst, int* __restrict__ deg, int ne) {
    int i = blockIdx.x * blockDim.x + threadIdx.x;
    if (i < ne) atomicAdd(&deg[dst[i]], 1);
}

__global__ void k_scanA(const int* __restrict__ deg, int* __restrict__ excl,
                        int* __restrict__ bsum, int n) {
    __shared__ int buf[256];
    int tid = threadIdx.x;
    int i = blockIdx.x * 256 + tid;
    int v = (i < n) ? deg[i] : 0;
    buf[tid] = v;
    __syncthreads();
    for (int off = 1; off < 256; off <<= 1) {
        int u = (tid >= off) ? buf[tid - off] : 0;
        __syncthreads();
        buf[tid] += u;
        __syncthreads();
    }
    int incl = buf[tid];
    if (i < n) excl[i] = incl - v;
    if (tid == 255) bsum[blockIdx.x] = incl;
}

__global__ void k_scanB(int* __restrict__ bsum, int nb) {
    __shared__ int buf[256];
    int tid = threadIdx.x;
    int v = (tid < nb) ? bsum[tid] : 0;
    buf[tid] = v;
    __syncthreads();
    for (int off = 1; off < 256; off <<= 1) {
        int u = (tid >= off) ? buf[tid - off] : 0;
        __syncthreads();
        buf[tid] += u;
        __syncthreads();
    }
    if (tid < nb) bsum[tid] = buf[tid] - v;
}

__global__ void k_scanC(int* __restrict__ rowptr, const int* __restrict__ bsum, int n, int total) {
    int i = blockIdx.x * 256 + threadIdx.x;
    if (i < n) rowptr[i] += bsum[i >> 8];
    if (i == 0) rowptr[n] = total;
}

__global__ void k_scatter(const int* __restrict__ src, const int* __restrict__ dst,
                          int* __restrict__ cursor, int* __restrict__ csr_src, int ne) {
    int i = blockIdx.x * blockDim.x + threadIdx.x;
    if (i < ne) {
        int d = dst[i];
        int p = atomicAdd(&cursor[d], 1);
        csr_src[p] = src[i];
    }
}

// ---------------- MFMA GEMM: out[M,N] = epi(gelu?(A[M,K]) @ Wt[N,K]^T + bias) ----------------
// Zero-LDS: each of 4 waves owns a 32x32 tile of the 64x64 block tile; A/B
// fragments are direct 16B global loads matching the mfma_f32_16x16x32_bf16
// operand layout (row = lane&15, k-octet = lane>>4).
// EPI: 0 = +bias ; 1 = relu ; 2 = skip blend s*(acc+bias)+(1-s)*oldx
template <int KK, bool GELU, int EPI>
__global__ __launch_bounds__(256) void k_mm(const bf16* __restrict__ A, int lda,
                                            const bf16* __restrict__ Wt,
                                            const float* __restrict__ bias,
                                            bf16* __restrict__ out, int ldo,
                                            const bf16* __restrict__ oldx,
                                            const void* __restrict__ skipp, int skip_idx,
                                            const int* __restrict__ dflag) {
    constexpr int NK = KK / 32;
    int tid = threadIdx.x;
    int w = tid >> 6, l = tid & 63;
    int wm = w >> 1, wn = w & 1;
    int r0 = blockIdx.x * 64 + wm * 32;
    int n0 = blockIdx.y * 64 + wn * 32;
    int lr = l & 15, kb = l >> 4;

    s16x8 af[2][NK], bfr[2][NK];
    #pragma unroll
    for (int mt = 0; mt < 2; ++mt)
        #pragma unroll
        for (int kf = 0; kf < NK; ++kf)
            af[mt][kf] = *(const s16x8*)(A + (size_t)(r0 + mt * 16 + lr) * lda + kf * 32 + kb * 8);
    if (GELU) {
        #pragma unroll
        for (int mt = 0; mt < 2; ++mt)
            #pragma unroll
            for (int kf = 0; kf < NK; ++kf)
                #pragma unroll
                for (int i = 0; i < 8; ++i) {
                    float v = __uint_as_float(((u32)(u16)af[mt][kf][i]) << 16);
                    v = 0.5f * v * (1.f + erff(v * 0.70710678118f));
                    af[mt][kf][i] = (short)f2bu(v);
                }
    }
    #pragma unroll
    for (int nt = 0; nt < 2; ++nt)
        #pragma unroll
        for (int kf = 0; kf < NK; ++kf)
            bfr[nt][kf] = *(const s16x8*)(Wt + (size_t)(n0 + nt * 16 + lr) * KK + kf * 32 + kb * 8);

    f32x4 acc[2][2] = {};
    #pragma unroll
    for (int kf = 0; kf < NK; ++kf)
        #pragma unroll
        for (int mt = 0; mt < 2; ++mt)
            #pragma unroll
            for (int nt = 0; nt < 2; ++nt)
                acc[mt][nt] = __builtin_amdgcn_mfma_f32_16x16x32_bf16(af[mt][kf], bfr[nt][kf], acc[mt][nt], 0, 0, 0);

    float sg = 0.f;
    if (EPI == 2) {
        float sv = ldf(skipp, skip_idx, dflag[0]);
        sg = 1.f / (1.f + expf(-sv));
    }
    #pragma unroll
    for (int mt = 0; mt < 2; ++mt)
        #pragma unroll
        for (int nt = 0; nt < 2; ++nt) {
            int col = n0 + nt * 16 + lr;
            float bv = bias[col];
            #pragma unroll
            for (int r = 0; r < 4; ++r) {
                int row = r0 + mt * 16 + kb * 4 + r;
                float o = acc[mt][nt][r] + bv;
                if (EPI == 1) o = fmaxf(o, 0.f);
                if (EPI == 2) o = sg * o + (1.f - sg) * bf2f(oldx[(size_t)row * 128 + col]);
                out[(size_t)row * ldo + col] = __float2bfloat16(o);
            }
        }
}

// ---------------- edge aggregation (softmax message passing) ----------------
// kv: src-side kqv bf16 [Nsrc][384] (0..127 scaled k', 256..383 v')
// qm: dst-side kqv bf16 [Ndst][384] (128..255 = q); output overwrites q-cols.
__global__ __launch_bounds__(256) void k_edge(const bf16* __restrict__ kv, bf16* __restrict__ qm,
                                              const int* __restrict__ rowptr,
                                              const int* __restrict__ csr_src, int n_dst) {
    int wave = threadIdx.x >> 6, lane = threadIdx.x & 63;
    int n = blockIdx.x * 4 + wave;
    if (n >= n_dst) return;
    int h = lane >> 4, j = lane & 15;
    int col = h * 32 + j * 2;
    bf16* qp = qm + (size_t)n * 384 + 128 + col;
    u32 qw = *(const u32*)qp;
    float qx = lo_bf(qw), qy = hi_bf(qw);
    float ax = 0.f, ay = 0.f, den = 0.f;
    int e0 = rowptr[n], e1 = rowptr[n + 1];
    int e = e0;
    for (; e + 2 <= e1; e += 2) {
        int s0 = csr_src[e], s1 = csr_src[e + 1];
        const bf16* b0 = kv + (size_t)s0 * 384;
        const bf16* b1 = kv + (size_t)s1 * 384;
        u32 kw0 = *(const u32*)(b0 + col);
        u32 kw1 = *(const u32*)(b1 + col);
        u32 vw0 = *(const u32*)(b0 + 256 + col);
        u32 vw1 = *(const u32*)(b1 + 256 + col);
        float p0 = qx * lo_bf(kw0) + qy * hi_bf(kw0);
        float p1 = qx * lo_bf(kw1) + qy * hi_bf(kw1);
        p0 += __shfl_xor(p0, 1);  p1 += __shfl_xor(p1, 1);
        p0 += __shfl_xor(p0, 2);  p1 += __shfl_xor(p1, 2);
        p0 += __shfl_xor(p0, 4);  p1 += __shfl_xor(p1, 4);
        p0 += __shfl_xor(p0, 8);  p1 += __shfl_xor(p1, 8);
        float w0 = expf(p0), w1 = expf(p1);
        den += w0 + w1;
        ax += w0 * lo_bf(vw0) + w1 * lo_bf(vw1);
        ay += w0 * hi_bf(vw0) + w1 * hi_bf(vw1);
    }
    if (e < e1) {
        int s0 = csr_src[e];
        const bf16* b0 = kv + (size_t)s0 * 384;
        u32 kw0 = *(const u32*)(b0 + col);
        u32 vw0 = *(const u32*)(b0 + 256 + col);
        float p0 = qx * lo_bf(kw0) + qy * hi_bf(kw0);
        p0 += __shfl_xor(p0, 1);
        p0 += __shfl_xor(p0, 2);
        p0 += __shfl_xor(p0, 4);
        p0 += __shfl_xor(p0, 8);
        float w0 = expf(p0);
        den += w0;
        ax += w0 * lo_bf(vw0);
        ay += w0 * hi_bf(vw0);
    }
    float inv = 1.f / (den + 1e-16f);
    u32 pk = (u32)f2bu(ax * inv) | ((u32)f2bu(ay * inv) << 16);
    *(u32*)qp = pk;
}

// ---------------- final output (adaptive dtype) ----------------
__global__ void k_out(const bf16* __restrict__ xa, const bf16* __restrict__ xb,
                      void* __restrict__ out, int n_each, const int* __restrict__ dflag) {
    int isb = dflag[0];
    int i = blockIdx.x * blockDim.x + threadIdx.x;
    if (i >= 2 * n_each) return;
    bf16 v = (i < n_each) ? xa[i] : xb[i - n_each];
    if (isb) ((bf16*)out)[i] = v;
    else     ((float*)out)[i] = bf2f(v);
}

extern "C" void kernel_launch(void* const* d_in, const int* in_sizes, int n_in,
                              void* d_out, int out_size, void* d_ws, size_t ws_size,
                              hipStream_t stream) {
    const void* x_a     = d_in[0];
    const void* x_b     = d_in[1];
    const int*  edge_ab = (const int*)d_in[2];
    const int*  edge_ba = (const int*)d_in[3];
    const void* lin_a_w = d_in[4];
    const void* lin_a_b = d_in[5];
    const void* lin_b_w = d_in[6];
    const void* lin_b_b = d_in[7];
    const void* k_w     = d_in[8];
    const void* k_b     = d_in[9];
    const void* q_w     = d_in[10];
    const void* q_b     = d_in[11];
    const void* v_w     = d_in[12];
    const void* v_b     = d_in[13];
    const void* a_rel   = d_in[14];
    const void* m_rel   = d_in[15];
    const void* p_rel   = d_in[16];
    const void* a_lin_w = d_in[17];
    const void* a_lin_b = d_in[18];
    const void* skip    = d_in[19];

    // -------- workspace layout: f32 block, bf16 block, int block --------
    char* p = (char*)d_ws;
    auto falloc = [&](size_t n) { float* r = (float*)p; p += n * sizeof(float); return r; };
    float* b_lin_a_f = falloc(128);
    float* b_lin_b_f = falloc(128);
    float* b_kqv     = falloc(4 * 384);
    float* b_alin    = falloc(4 * 128);
    auto halloc = [&](size_t n) { bf16* r = (bf16*)p; p += n * sizeof(bf16); return r; };
    bf16* x_a_bf  = halloc((size_t)NAn * 64);
    bf16* x_b_bf  = halloc((size_t)NBn * 32);
    bf16* xa_bf   = halloc((size_t)NAn * Cc);
    bf16* xb_bf   = halloc((size_t)NBn * Cc);
    bf16* kqv_a   = halloc((size_t)NAn * 384);
    bf16* kqv_b   = halloc((size_t)NBn * 384);
    bf16* wt_lin_a = halloc(128 * 64);
    bf16* wt_lin_b = halloc(128 * 32);
    bf16* wt_kqv   = halloc(4 * 384 * 128);
    bf16* wt_alin  = halloc(4 * 128 * 128);
    auto ialloc = [&](size_t n) { int* r = (int*)p; p += n * sizeof(int); return r; };
    int* dflag     = ialloc(4);
    int* rowptr_ab = ialloc(NBn + 1);
    int* rowptr_ba = ialloc(NAn + 1);
    int* deg_ab    = ialloc(NBn);
    int* deg_ba    = ialloc(NAn);
    int* cursor_ab = ialloc(NBn);
    int* cursor_ba = ialloc(NAn);
    int* bsum_ab   = ialloc(256);
    int* bsum_ba   = ialloc(256);
    int* csr_ab    = ialloc(NEe);
    int* csr_ba    = ialloc(NEe);

    // -------- dtype detection --------
    k_detect<<<1, 256, 0, stream>>>((const u16*)x_a, 8192, dflag);

    // -------- weight prep --------
    k_convert<<<1, 128, 0, stream>>>(lin_a_b, b_lin_a_f, 128, dflag);
    k_convert<<<1, 128, 0, stream>>>(lin_b_b, b_lin_b_f, 128, dflag);
    k_convert<<<2, 256, 0, stream>>>(a_lin_b, b_alin, 512, dflag);
    k_tw<<<dim3((64 * 128 + 255) / 256, 1), 256, 0, stream>>>(lin_a_w, wt_lin_a, 64, 128, dflag);
    k_tw<<<dim3((32 * 128 + 255) / 256, 1), 256, 0, stream>>>(lin_b_w, wt_lin_b, 32, 128, dflag);
    k_tw<<<dim3((128 * 128 + 255) / 256, 4), 256, 0, stream>>>(a_lin_w, wt_alin, 128, 128, dflag);
    k_prep_kqv_w<<<512, 384, 0, stream>>>(k_w, q_w, v_w, a_rel, m_rel, p_rel, wt_kqv, dflag);
    k_prep_kqv_b<<<4, 384, 0, stream>>>(k_b, q_b, v_b, a_rel, m_rel, p_rel, b_kqv, dflag);

    // -------- x inputs -> bf16 --------
    k_convb<<<(NAn * 64 + 255) / 256, 256, 0, stream>>>(x_a, x_a_bf, NAn * 64, dflag);
    k_convb<<<(NBn * 32 + 255) / 256, 256, 0, stream>>>(x_b, x_b_bf, NBn * 32, dflag);

    // -------- CSR build (group by dst) --------
    hipMemsetAsync(deg_ab, 0, NBn * sizeof(int), stream);
    hipMemsetAsync(deg_ba, 0, NAn * sizeof(int), stream);
    k_hist<<<(NEe + 255) / 256, 256, 0, stream>>>(edge_ab + NEe, deg_ab, NEe);
    k_hist<<<(NEe + 255) / 256, 256, 0, stream>>>(edge_ba + NEe, deg_ba, NEe);
    int nblk = (NBn + 255) / 256; // 157
    k_scanA<<<nblk, 256, 0, stream>>>(deg_ab, rowptr_ab, bsum_ab, NBn);
    k_scanA<<<nblk, 256, 0, stream>>>(deg_ba, rowptr_ba, bsum_ba, NAn);
    k_scanB<<<1, 256, 0, stream>>>(bsum_ab, nblk);
    k_scanB<<<1, 256, 0, stream>>>(bsum_ba, nblk);
    k_scanC<<<nblk, 256, 0, stream>>>(rowptr_ab, bsum_ab, NBn, NEe);
    k_scanC<<<nblk, 256, 0, stream>>>(rowptr_ba, bsum_ba, NAn, NEe);
    hipMemcpyAsync(cursor_ab, rowptr_ab, NBn * sizeof(int), hipMemcpyDeviceToDevice, stream);
    hipMemcpyAsync(cursor_ba, rowptr_ba, NAn * sizeof(int), hipMemcpyDeviceToDevice, stream);
    k_scatter<<<(NEe + 255) / 256, 256, 0, stream>>>(edge_ab, edge_ab + NEe, cursor_ab, csr_ab, NEe);
    k_scatter<<<(NEe + 255) / 256, 256, 0, stream>>>(edge_ba, edge_ba + NEe, cursor_ba, csr_ba, NEe);

    // -------- input linears + relu --------
    k_mm<64, false, 1><<<dim3(NAn / 64, 2), 256, 0, stream>>>(
        x_a_bf, 64, wt_lin_a, b_lin_a_f, xa_bf, 128, nullptr, nullptr, 0, dflag);
    k_mm<32, false, 1><<<dim3(NBn / 64, 2), 256, 0, stream>>>(
        x_b_bf, 32, wt_lin_b, b_lin_b_f, xb_bf, 128, nullptr, nullptr, 0, dflag);

    // -------- layers --------
    for (int l = 0; l < Ll; ++l) {
        int lt0 = l * 2 + 0, lt1 = l * 2 + 1;
        k_mm<128, false, 0><<<dim3(NAn / 64, 6), 256, 0, stream>>>(
            xa_bf, 128, wt_kqv + (size_t)lt0 * 384 * 128, b_kqv + (size_t)lt0 * 384,
            kqv_a, 384, nullptr, nullptr, 0, dflag);
        k_mm<128, false, 0><<<dim3(NBn / 64, 6), 256, 0, stream>>>(
            xb_bf, 128, wt_kqv + (size_t)lt1 * 384 * 128, b_kqv + (size_t)lt1 * 384,
            kqv_b, 384, nullptr, nullptr, 0, dflag);
        // edge AB: k/v from A, q from B -> attn_b into kqv_b q-cols
        k_edge<<<(NBn + 3) / 4, 256, 0, stream>>>(kqv_a, kqv_b, rowptr_ab, csr_ab, NBn);
        // edge BA: k/v from B, q from A -> attn_a into kqv_a q-cols
        k_edge<<<(NAn + 3) / 4, 256, 0, stream>>>(kqv_b, kqv_a, rowptr_ba, csr_ba, NAn);
        // a_lin(gelu(attn)) + sigmoid-skip blend, updates xa_bf/xb_bf in place
        k_mm<128, true, 2><<<dim3(NAn / 64, 2), 256, 0, stream>>>(
            kqv_a + 128, 384, wt_alin + (size_t)lt0 * 128 * 128, b_alin + (size_t)lt0 * 128,
            xa_bf, 128, xa_bf, skip, lt0, dflag);
        k_mm<128, true, 2><<<dim3(NBn / 64, 2), 256, 0, stream>>>(
            kqv_b + 128, 384, wt_alin + (size_t)lt1 * 128 * 128, b_alin + (size_t)lt1 * 128,
            xb_bf, 128, xb_bf, skip, lt1, dflag);
    }

    // -------- output --------
    int n_each = NAn * Cc;
    k_out<<<(2 * n_each + 255) / 256, 256, 0, stream>>>(xa_bf, xb_bf, d_out, n_each, dflag);
}

// Round 4
// 329.723 us; speedup vs baseline: 2.2254x; 1.4338x over previous
//
#include <hip/hip_runtime.h>
#include <hip/hip_bf16.h>
#include <math.h>

#define NAn 40000
#define NBn 40000
#define NEe 250000
#define Cc 128
#define Hh 4
#define Ll 2
static constexpr float INV_SQRT_D = 0.17677669529663687f; // 1/sqrt(32)

typedef __hip_bfloat16 bf16;
typedef unsigned short u16;
typedef unsigned int u32;
typedef short s16x8 __attribute__((ext_vector_type(8)));
typedef float f32x4 __attribute__((ext_vector_type(4)));

__device__ __forceinline__ float bf2f(bf16 x) { return __bfloat162float(x); }
__device__ __forceinline__ float lo_bf(u32 w) { return __uint_as_float(w << 16); }
__device__ __forceinline__ float hi_bf(u32 w) { return __uint_as_float(w & 0xffff0000u); }
__device__ __forceinline__ float ldf(const void* p, size_t i, int isb) {
    return isb ? bf2f(((const bf16*)p)[i]) : ((const float*)p)[i];
}
__device__ __forceinline__ u16 f2bu(float v) {
    union { bf16 b; u16 u; } c; c.b = __float2bfloat16(v); return c.u;
}
__device__ __forceinline__ float gelu_f(float v) {
    return 0.5f * v * (1.f + erff(v * 0.70710678118f));
}

// ---------------- dtype detection ----------------
__global__ void k_detect(const u16* __restrict__ x, int n, int* __restrict__ flag) {
    __shared__ float smax[256];
    int tid = threadIdx.x;
    float m = 0.f;
    for (int i = tid; i < n; i += 256) {
        float v = fabsf(__uint_as_float(((u32)x[i]) << 16));
        if (v != v) v = 1e30f;
        m = fmaxf(m, v);
    }
    smax[tid] = m;
    __syncthreads();
    for (int s = 128; s > 0; s >>= 1) {
        if (tid < s) smax[tid] = fmaxf(smax[tid], smax[tid + s]);
        __syncthreads();
    }
    if (tid == 0) flag[0] = (smax[0] > 1e4f) ? 0 : 1;
}

// ---------------- merged x-input convert (x_a then x_b) ----------------
__global__ void k_convb(const void* __restrict__ xa, const void* __restrict__ xb,
                        bf16* __restrict__ da, bf16* __restrict__ db,
                        const int* __restrict__ dflag) {
    int isb = dflag[0];
    int i = blockIdx.x * 256 + threadIdx.x;
    int na = NAn * 64;
    if (i < na) da[i] = isb ? ((const bf16*)xa)[i] : __float2bfloat16(((const float*)xa)[i]);
    else if (i < na + NBn * 32) {
        int j = i - na;
        db[j] = isb ? ((const bf16*)xb)[j] : __float2bfloat16(((const float*)xb)[j]);
    }
}

// ---------------- merged small weight prep (384 threads) ----------------
// blocks [0,2): bias_lin[768] = {lin_a_b,lin_b_b,a_lin_b}
// blocks [2,205): transposes wt_lin_a(8192) | wt_lin_b(4096) | wt_alin(65536)
// blocks [205,209): kqv bias per lt (layout [k|v|q])
__global__ void k_prep_small(const void* __restrict__ lin_a_w, const void* __restrict__ lin_a_b,
                             const void* __restrict__ lin_b_w, const void* __restrict__ lin_b_b,
                             const void* __restrict__ a_lin_w, const void* __restrict__ a_lin_b,
                             const void* __restrict__ k_b, const void* __restrict__ q_b,
                             const void* __restrict__ v_b, const void* __restrict__ a_rel,
                             const void* __restrict__ m_rel, const void* __restrict__ p_rel,
                             float* __restrict__ bias_lin, bf16* __restrict__ wt_lin_a,
                             bf16* __restrict__ wt_lin_b, bf16* __restrict__ wt_alin,
                             float* __restrict__ b_kqv, const int* __restrict__ dflag) {
    int isb = dflag[0];
    int b = blockIdx.x, t = threadIdx.x;
    if (b < 2) {
        int i = b * 384 + t;
        if (i < 768) {
            float v = (i < 128) ? ldf(lin_a_b, i, isb)
                    : (i < 256) ? ldf(lin_b_b, i - 128, isb)
                                : ldf(a_lin_b, i - 256, isb);
            bias_lin[i] = v;
        }
    } else if (b < 205) {
        int e = (b - 2) * 384 + t;
        if (e < 8192) {            // wt_lin_a [128][64]
            int n = e >> 6, k = e & 63;
            wt_lin_a[e] = __float2bfloat16(ldf(lin_a_w, (size_t)k * 128 + n, isb));
        } else if (e < 12288) {    // wt_lin_b [128][32]
            int r = e - 8192; int n = r >> 5, k = r & 31;
            wt_lin_b[r] = __float2bfloat16(ldf(lin_b_w, (size_t)k * 128 + n, isb));
        } else if (e < 77824) {    // wt_alin [4][128][128]
            int r = e - 12288; int s = r >> 14, rem = r & 16383;
            int n = rem >> 7, k = rem & 127;
            wt_alin[r] = __float2bfloat16(ldf(a_lin_w, (size_t)s * 16384 + (size_t)k * 128 + n, isb));
        }
    } else {                       // kqv bias, lt = b-205, j = t; layout [k|v|q]
        int lt = b - 205, j = t;
        float out;
        if (j < 128) {
            int h = j >> 5, e = j & 31;
            float s = ldf(p_rel, lt * Hh + h, isb) * INV_SQRT_D;
            float sum = 0.f;
            size_t kb0 = (size_t)lt * 128 + h * 32;
            size_t ar0 = ((size_t)lt * Hh + h) * 1024 + e;
            #pragma unroll
            for (int d = 0; d < 32; ++d) sum += ldf(k_b, kb0 + d, isb) * ldf(a_rel, ar0 + d * 32, isb);
            out = sum * s;
        } else if (j < 256) {
            int jj = j - 128; int h = jj >> 5, e = jj & 31;
            float sum = 0.f;
            size_t vb0 = (size_t)lt * 128 + h * 32;
            size_t mr0 = ((size_t)lt * Hh + h) * 1024 + e;
            #pragma unroll
            for (int d = 0; d < 32; ++d) sum += ldf(v_b, vb0 + d, isb) * ldf(m_rel, mr0 + d * 32, isb);
            out = sum;
        } else {
            out = ldf(q_b, (size_t)lt * 128 + (j - 256), isb);
        }
        b_kqv[(size_t)lt * 384 + j] = out;
    }
}

// ---------------- fused KQV weight prep: Wt[lt][384][128] bf16, layout [k|v|q] ----------------
__global__ void k_prep_kqv_w(const void* __restrict__ k_w, const void* __restrict__ q_w,
                             const void* __restrict__ v_w, const void* __restrict__ a_rel,
                             const void* __restrict__ m_rel, const void* __restrict__ p_rel,
                             bf16* __restrict__ Wt, const int* __restrict__ dflag) {
    int isb = dflag[0];
    int b = blockIdx.x;          // lt*128 + c (c = K index)
    int lt = b >> 7, c = b & 127;
    int j = threadIdx.x;         // 0..383 (N index)
    float out;
    if (j < 128) {               // k' scaled
        int h = j >> 5, e = j & 31;
        float s = ldf(p_rel, lt * Hh + h, isb) * INV_SQRT_D;
        float sum = 0.f;
        size_t kw0 = ((size_t)lt * 128 + c) * 128 + h * 32;
        size_t ar0 = ((size_t)lt * Hh + h) * 1024 + e;
        #pragma unroll
        for (int d = 0; d < 32; ++d) sum += ldf(k_w, kw0 + d, isb) * ldf(a_rel, ar0 + d * 32, isb);
        out = sum * s;
    } else if (j < 256) {        // v'
        int jj = j - 128; int h = jj >> 5, e = jj & 31;
        float sum = 0.f;
        size_t vw0 = ((size_t)lt * 128 + c) * 128 + h * 32;
        size_t mr0 = ((size_t)lt * Hh + h) * 1024 + e;
        #pragma unroll
        for (int d = 0; d < 32; ++d) sum += ldf(v_w, vw0 + d, isb) * ldf(m_rel, mr0 + d * 32, isb);
        out = sum;
    } else {                     // q
        out = ldf(q_w, ((size_t)lt * 128 + c) * 128 + (j - 256), isb);
    }
    Wt[((size_t)lt * 384 + j) * 128 + c] = __float2bfloat16(out);
}

// ---------------- CSR build (both directions per launch, y = dir) ----------------
__global__ void k_hist(const int* __restrict__ d0, const int* __restrict__ d1,
                       int* __restrict__ deg0, int* __restrict__ deg1) {
    int i = blockIdx.x * 256 + threadIdx.x;
    if (i >= NEe) return;
    if (blockIdx.y == 0) atomicAdd(&deg0[d0[i]], 1);
    else                 atomicAdd(&deg1[d1[i]], 1);
}

__global__ void k_scanA(const int* __restrict__ deg0, const int* __restrict__ deg1,
                        int* __restrict__ ex0, int* __restrict__ ex1,
                        int* __restrict__ bs0, int* __restrict__ bs1, int n) {
    const int* deg = blockIdx.y ? deg1 : deg0;
    int* excl = blockIdx.y ? ex1 : ex0;
    int* bsum = blockIdx.y ? bs1 : bs0;
    __shared__ int buf[256];
    int tid = threadIdx.x;
    int i = blockIdx.x * 256 + tid;
    int v = (i < n) ? deg[i] : 0;
    buf[tid] = v;
    __syncthreads();
    for (int off = 1; off < 256; off <<= 1) {
        int u = (tid >= off) ? buf[tid - off] : 0;
        __syncthreads();
        buf[tid] += u;
        __syncthreads();
    }
    int incl = buf[tid];
    if (i < n) excl[i] = incl - v;
    if (tid == 255) bsum[blockIdx.x] = incl;
}

__global__ void k_scanB(int* __restrict__ bs0, int* __restrict__ bs1, int nb) {
    int* bsum = blockIdx.x ? bs1 : bs0;
    __shared__ int buf[256];
    int tid = threadIdx.x;
    int v = (tid < nb) ? bsum[tid] : 0;
    buf[tid] = v;
    __syncthreads();
    for (int off = 1; off < 256; off <<= 1) {
        int u = (tid >= off) ? buf[tid - off] : 0;
        __syncthreads();
        buf[tid] += u;
        __syncthreads();
    }
    if (tid < nb) bsum[tid] = buf[tid] - v;
}

// adds block offsets AND writes cursor copy (replaces memcpy)
__global__ void k_scanC(int* __restrict__ rp0, int* __restrict__ rp1,
                        const int* __restrict__ bs0, const int* __restrict__ bs1,
                        int* __restrict__ cur0, int* __restrict__ cur1, int n) {
    int* rowptr = blockIdx.y ? rp1 : rp0;
    const int* bsum = blockIdx.y ? bs1 : bs0;
    int* cursor = blockIdx.y ? cur1 : cur0;
    int i = blockIdx.x * 256 + threadIdx.x;
    if (i < n) {
        int v = rowptr[i] + bsum[i >> 8];
        rowptr[i] = v;
        cursor[i] = v;
    }
    if (i == 0) rowptr[n] = NEe;
}

__global__ void k_scatter(const int* __restrict__ e0, const int* __restrict__ e1,
                          int* __restrict__ cur0, int* __restrict__ cur1,
                          int* __restrict__ cs0, int* __restrict__ cs1) {
    int i = blockIdx.x * 256 + threadIdx.x;
    if (i >= NEe) return;
    const int* e = blockIdx.y ? e1 : e0;
    int* cursor = blockIdx.y ? cur1 : cur0;
    int* csr = blockIdx.y ? cs1 : cs0;
    int d = e[NEe + i];
    int p = atomicAdd(&cursor[d], 1);
    csr[p] = e[i];
}

// ---------------- MFMA GEMM, N-loop, reg-double-buffered B, fused type pair ----------------
// block = 4 waves; wave w: rows blockIdx.x*64 + (w&1)*32, N-half (w>>1).
// blockIdx.y selects the (A,W,bias,out,old,skip) set (fused A-type/B-type pair).
// EPI: 0 = +bias ; 1 = relu ; 2 = skip blend s*(acc+bias)+(1-s)*oldx (ldo must be 128 for oldx)
template <int KK, int NSTEPS, int EPI>
__global__ __launch_bounds__(256) void k_mm2(const bf16* __restrict__ A0, const bf16* __restrict__ A1,
                                             int lda,
                                             const bf16* __restrict__ W0, const bf16* __restrict__ W1,
                                             const float* __restrict__ bias0, const float* __restrict__ bias1,
                                             bf16* __restrict__ out0, bf16* __restrict__ out1, int ldo,
                                             const bf16* __restrict__ old0, const bf16* __restrict__ old1,
                                             const void* __restrict__ skipp, int si0, int si1,
                                             const int* __restrict__ dflag) {
    constexpr int NK = KK / 32;
    int y = blockIdx.y;
    const bf16* A = y ? A1 : A0;
    const bf16* Wt = y ? W1 : W0;
    const float* bias = y ? bias1 : bias0;
    bf16* out = y ? out1 : out0;
    const bf16* oldx = y ? old1 : old0;
    int skip_idx = y ? si1 : si0;

    int tid = threadIdx.x;
    int w = tid >> 6, l = tid & 63;
    int r0 = blockIdx.x * 64 + (w & 1) * 32;
    int n0base = (w >> 1) * (NSTEPS * 32);
    int lr = l & 15, kb = l >> 4;

    s16x8 af[2][NK];
    #pragma unroll
    for (int mt = 0; mt < 2; ++mt)
        #pragma unroll
        for (int kf = 0; kf < NK; ++kf)
            af[mt][kf] = *(const s16x8*)(A + (size_t)(r0 + mt * 16 + lr) * lda + kf * 32 + kb * 8);

    s16x8 bfr[2][2][NK];
    #pragma unroll
    for (int nt = 0; nt < 2; ++nt)
        #pragma unroll
        for (int kf = 0; kf < NK; ++kf)
            bfr[0][nt][kf] = *(const s16x8*)(Wt + (size_t)(n0base + nt * 16 + lr) * KK + kf * 32 + kb * 8);

    float sg = 0.f;
    if (EPI == 2) {
        float sv = ldf(skipp, skip_idx, dflag[0]);
        sg = 1.f / (1.f + expf(-sv));
    }

    #pragma unroll
    for (int s = 0; s < NSTEPS; ++s) {
        int n0 = n0base + s * 32;
        if (s + 1 < NSTEPS) {
            #pragma unroll
            for (int nt = 0; nt < 2; ++nt)
                #pragma unroll
                for (int kf = 0; kf < NK; ++kf)
                    bfr[(s + 1) & 1][nt][kf] =
                        *(const s16x8*)(Wt + (size_t)(n0 + 32 + nt * 16 + lr) * KK + kf * 32 + kb * 8);
        }
        f32x4 acc[2][2] = {};
        #pragma unroll
        for (int kf = 0; kf < NK; ++kf)
            #pragma unroll
            for (int mt = 0; mt < 2; ++mt)
                #pragma unroll
                for (int nt = 0; nt < 2; ++nt)
                    acc[mt][nt] = __builtin_amdgcn_mfma_f32_16x16x32_bf16(
                        af[mt][kf], bfr[s & 1][nt][kf], acc[mt][nt], 0, 0, 0);
        #pragma unroll
        for (int mt = 0; mt < 2; ++mt)
            #pragma unroll
            for (int nt = 0; nt < 2; ++nt) {
                int col = n0 + nt * 16 + lr;
                float bv = bias[col];
                #pragma unroll
                for (int r = 0; r < 4; ++r) {
                    int row = r0 + mt * 16 + kb * 4 + r;
                    float o = acc[mt][nt][r] + bv;
                    if (EPI == 1) o = fmaxf(o, 0.f);
                    if (EPI == 2) o = sg * o + (1.f - sg) * bf2f(oldx[(size_t)row * 128 + col]);
                    out[(size_t)row * ldo + col] = __float2bfloat16(o);
                }
            }
    }
}

// ---------------- fused edge aggregation, both directions, GELU epilogue ----------------
// kqv layout [k(0:128) | v(128:256) | q(256:384)]. Writes gelu(attn) into q-cols.
__global__ __launch_bounds__(256) void k_edge(const bf16* __restrict__ kv0, bf16* __restrict__ qm0,
                                              const int* __restrict__ rp0, const int* __restrict__ cs0,
                                              const bf16* __restrict__ kv1, bf16* __restrict__ qm1,
                                              const int* __restrict__ rp1, const int* __restrict__ cs1,
                                              int nblk0) {
    int dir = (blockIdx.x >= nblk0);
    int blk = dir ? (blockIdx.x - nblk0) : blockIdx.x;
    const bf16* kv = dir ? kv1 : kv0;
    bf16* qm = dir ? qm1 : qm0;
    const int* rowptr = dir ? rp1 : rp0;
    const int* csr = dir ? cs1 : cs0;

    int wave = threadIdx.x >> 6, lane = threadIdx.x & 63;
    int n = blk * 4 + wave;
    if (n >= NAn) return; // NAn == NBn
    int h = lane >> 4, j = lane & 15;
    int col = h * 32 + j * 2;
    bf16* qp = qm + (size_t)n * 384 + 256 + col;
    u32 qw = *(const u32*)qp;
    float qx = lo_bf(qw), qy = hi_bf(qw);
    float ax = 0.f, ay = 0.f, den = 0.f;
    int e0 = rowptr[n], e1 = rowptr[n + 1];
    int e = e0;
    for (; e + 4 <= e1; e += 4) {
        int s0 = csr[e], s1 = csr[e + 1], s2 = csr[e + 2], s3 = csr[e + 3];
        const bf16* b0 = kv + (size_t)s0 * 384;
        const bf16* b1 = kv + (size_t)s1 * 384;
        const bf16* b2 = kv + (size_t)s2 * 384;
        const bf16* b3 = kv + (size_t)s3 * 384;
        u32 k0 = *(const u32*)(b0 + col), k1 = *(const u32*)(b1 + col);
        u32 k2 = *(const u32*)(b2 + col), k3 = *(const u32*)(b3 + col);
        u32 v0 = *(const u32*)(b0 + 128 + col), v1 = *(const u32*)(b1 + 128 + col);
        u32 v2 = *(const u32*)(b2 + 128 + col), v3 = *(const u32*)(b3 + 128 + col);
        float p0 = qx * lo_bf(k0) + qy * hi_bf(k0);
        float p1 = qx * lo_bf(k1) + qy * hi_bf(k1);
        float p2 = qx * lo_bf(k2) + qy * hi_bf(k2);
        float p3 = qx * lo_bf(k3) + qy * hi_bf(k3);
        #pragma unroll
        for (int m = 1; m <= 8; m <<= 1) {
            p0 += __shfl_xor(p0, m); p1 += __shfl_xor(p1, m);
            p2 += __shfl_xor(p2, m); p3 += __shfl_xor(p3, m);
        }
        float w0 = expf(p0), w1 = expf(p1), w2 = expf(p2), w3 = expf(p3);
        den += (w0 + w1) + (w2 + w3);
        ax += w0 * lo_bf(v0) + w1 * lo_bf(v1) + w2 * lo_bf(v2) + w3 * lo_bf(v3);
        ay += w0 * hi_bf(v0) + w1 * hi_bf(v1) + w2 * hi_bf(v2) + w3 * hi_bf(v3);
    }
    for (; e < e1; ++e) {
        int s0 = csr[e];
        const bf16* b0 = kv + (size_t)s0 * 384;
        u32 k0 = *(const u32*)(b0 + col);
        u32 v0 = *(const u32*)(b0 + 128 + col);
        float p0 = qx * lo_bf(k0) + qy * hi_bf(k0);
        #pragma unroll
        for (int m = 1; m <= 8; m <<= 1) p0 += __shfl_xor(p0, m);
        float w0 = expf(p0);
        den += w0;
        ax += w0 * lo_bf(v0);
        ay += w0 * hi_bf(v0);
    }
    float inv = 1.f / (den + 1e-16f);
    u32 pk = (u32)f2bu(gelu_f(ax * inv)) | ((u32)f2bu(gelu_f(ay * inv)) << 16);
    *(u32*)qp = pk;
}

// ---------------- final output (adaptive dtype) ----------------
__global__ void k_out(const bf16* __restrict__ xa, const bf16* __restrict__ xb,
                      void* __restrict__ out, int n_each, const int* __restrict__ dflag) {
    int isb = dflag[0];
    int i = blockIdx.x * blockDim.x + threadIdx.x;
    if (i >= 2 * n_each) return;
    bf16 v = (i < n_each) ? xa[i] : xb[i - n_each];
    if (isb) ((bf16*)out)[i] = v;
    else     ((float*)out)[i] = bf2f(v);
}

extern "C" void kernel_launch(void* const* d_in, const int* in_sizes, int n_in,
                              void* d_out, int out_size, void* d_ws, size_t ws_size,
                              hipStream_t stream) {
    const void* x_a     = d_in[0];
    const void* x_b     = d_in[1];
    const int*  edge_ab = (const int*)d_in[2];
    const int*  edge_ba = (const int*)d_in[3];
    const void* lin_a_w = d_in[4];
    const void* lin_a_b = d_in[5];
    const void* lin_b_w = d_in[6];
    const void* lin_b_b = d_in[7];
    const void* k_w     = d_in[8];
    const void* k_b     = d_in[9];
    const void* q_w     = d_in[10];
    const void* q_b     = d_in[11];
    const void* v_w     = d_in[12];
    const void* v_b     = d_in[13];
    const void* a_rel   = d_in[14];
    const void* m_rel   = d_in[15];
    const void* p_rel   = d_in[16];
    const void* a_lin_w = d_in[17];
    const void* a_lin_b = d_in[18];
    const void* skip    = d_in[19];

    // -------- workspace layout --------
    char* p = (char*)d_ws;
    auto falloc = [&](size_t n) { float* r = (float*)p; p += n * sizeof(float); return r; };
    float* bias_lin = falloc(768);       // [lin_a_b | lin_b_b | a_lin_b(512)]
    float* b_kqv    = falloc(4 * 384);
    auto halloc = [&](size_t n) { bf16* r = (bf16*)p; p += n * sizeof(bf16); return r; };
    bf16* x_a_bf   = halloc((size_t)NAn * 64);
    bf16* x_b_bf   = halloc((size_t)NBn * 32);
    bf16* xa_bf    = halloc((size_t)NAn * Cc);
    bf16* xb_bf    = halloc((size_t)NBn * Cc);
    bf16* kqv_a    = halloc((size_t)NAn * 384);
    bf16* kqv_b    = halloc((size_t)NBn * 384);
    bf16* wt_lin_a = halloc(128 * 64);
    bf16* wt_lin_b = halloc(128 * 32);
    bf16* wt_kqv   = halloc(4 * 384 * 128);
    bf16* wt_alin  = halloc(4 * 128 * 128);
    auto ialloc = [&](size_t n) { int* r = (int*)p; p += n * sizeof(int); return r; };
    int* dflag     = ialloc(4);
    int* rowptr_ab = ialloc(NBn + 1);
    int* rowptr_ba = ialloc(NAn + 1);
    int* deg_ab    = ialloc(NBn);       // deg_ab/deg_ba adjacent -> one memset
    int* deg_ba    = ialloc(NAn);
    int* cursor_ab = ialloc(NBn);
    int* cursor_ba = ialloc(NAn);
    int* bsum_ab   = ialloc(256);
    int* bsum_ba   = ialloc(256);
    int* csr_ab    = ialloc(NEe);
    int* csr_ba    = ialloc(NEe);

    // -------- dtype detection --------
    k_detect<<<1, 256, 0, stream>>>((const u16*)x_a, 8192, dflag);

    // -------- weight prep (2 launches) --------
    k_prep_small<<<209, 384, 0, stream>>>(lin_a_w, lin_a_b, lin_b_w, lin_b_b, a_lin_w, a_lin_b,
                                          k_b, q_b, v_b, a_rel, m_rel, p_rel,
                                          bias_lin, wt_lin_a, wt_lin_b, wt_alin, b_kqv, dflag);
    k_prep_kqv_w<<<512, 384, 0, stream>>>(k_w, q_w, v_w, a_rel, m_rel, p_rel, wt_kqv, dflag);

    // -------- x inputs -> bf16 (1 launch) --------
    k_convb<<<(NAn * 64 + NBn * 32 + 255) / 256, 256, 0, stream>>>(x_a, x_b, x_a_bf, x_b_bf, dflag);

    // -------- CSR build, both directions (5 launches + 1 memset) --------
    hipMemsetAsync(deg_ab, 0, 2 * NAn * sizeof(int), stream);
    dim3 eg((NEe + 255) / 256, 2);
    k_hist<<<eg, 256, 0, stream>>>(edge_ab + NEe, edge_ba + NEe, deg_ab, deg_ba);
    int nblk = (NBn + 255) / 256; // 157
    k_scanA<<<dim3(nblk, 2), 256, 0, stream>>>(deg_ab, deg_ba, rowptr_ab, rowptr_ba,
                                               bsum_ab, bsum_ba, NBn);
    k_scanB<<<2, 256, 0, stream>>>(bsum_ab, bsum_ba, nblk);
    k_scanC<<<dim3(nblk, 2), 256, 0, stream>>>(rowptr_ab, rowptr_ba, bsum_ab, bsum_ba,
                                               cursor_ab, cursor_ba, NBn);
    k_scatter<<<eg, 256, 0, stream>>>(edge_ab, edge_ba, cursor_ab, cursor_ba, csr_ab, csr_ba);

    // -------- input linears + relu (2 launches; K differs) --------
    k_mm2<64, 2, 1><<<dim3(NAn / 64, 1), 256, 0, stream>>>(
        x_a_bf, x_a_bf, 64, wt_lin_a, wt_lin_a, bias_lin, bias_lin,
        xa_bf, xa_bf, 128, nullptr, nullptr, nullptr, 0, 0, dflag);
    k_mm2<32, 2, 1><<<dim3(NBn / 64, 1), 256, 0, stream>>>(
        x_b_bf, x_b_bf, 32, wt_lin_b, wt_lin_b, bias_lin + 128, bias_lin + 128,
        xb_bf, xb_bf, 128, nullptr, nullptr, nullptr, 0, 0, dflag);

    // -------- layers (3 launches each) --------
    for (int l = 0; l < Ll; ++l) {
        int lt0 = l * 2 + 0, lt1 = l * 2 + 1;
        // fused kqv for both types
        k_mm2<128, 6, 0><<<dim3(NAn / 64, 2), 256, 0, stream>>>(
            xa_bf, xb_bf, 128,
            wt_kqv + (size_t)lt0 * 384 * 128, wt_kqv + (size_t)lt1 * 384 * 128,
            b_kqv + (size_t)lt0 * 384, b_kqv + (size_t)lt1 * 384,
            kqv_a, kqv_b, 384, nullptr, nullptr, nullptr, 0, 0, dflag);
        // fused edges, both directions (AB writes into kqv_b q-cols, BA into kqv_a q-cols)
        int nblk0 = (NBn + 3) / 4;
        k_edge<<<nblk0 + (NAn + 3) / 4, 256, 0, stream>>>(
            kqv_a, kqv_b, rowptr_ab, csr_ab,
            kqv_b, kqv_a, rowptr_ba, csr_ba, nblk0);
        // fused a_lin + skip blend for both types (GELU already applied in k_edge)
        k_mm2<128, 2, 2><<<dim3(NAn / 64, 2), 256, 0, stream>>>(
            kqv_a + 256, kqv_b + 256, 384,
            wt_alin + (size_t)lt0 * 128 * 128, wt_alin + (size_t)lt1 * 128 * 128,
            bias_lin + 256 + (size_t)lt0 * 128, bias_lin + 256 + (size_t)lt1 * 128,
            xa_bf, xb_bf, 128, xa_bf, xb_bf, skip, lt0, lt1, dflag);
    }

    // -------- output --------
    int n_each = NAn * Cc;
    k_out<<<(2 * n_each + 255) / 256, 256, 0, stream>>>(xa_bf, xb_bf, d_out, n_each, dflag);
}

// Round 7
// 320.845 us; speedup vs baseline: 2.2870x; 1.0277x over previous
//
#include <hip/hip_runtime.h>
#include <hip/hip_bf16.h>
#include <math.h>

#define NAn 40000
#define NBn 40000
#define NEe 250000
#define Cc 128
#define Hh 4
#define Ll 2
static constexpr float INV_SQRT_D = 0.17677669529663687f; // 1/sqrt(32)
static constexpr float LOG2E = 1.4426950408889634f;

typedef __hip_bfloat16 bf16;
typedef unsigned short u16;
typedef unsigned int u32;
typedef short s16x8 __attribute__((ext_vector_type(8)));
typedef float f32x4 __attribute__((ext_vector_type(4)));

__device__ __forceinline__ float bf2f(bf16 x) { return __bfloat162float(x); }
__device__ __forceinline__ float lo_bf(u32 w) { return __uint_as_float(w << 16); }
__device__ __forceinline__ float hi_bf(u32 w) { return __uint_as_float(w & 0xffff0000u); }
__device__ __forceinline__ float ldf(const void* p, size_t i, int isb) {
    return isb ? bf2f(((const bf16*)p)[i]) : ((const float*)p)[i];
}
__device__ __forceinline__ u16 f2bu(float v) {
    union { bf16 b; u16 u; } c; c.b = __float2bfloat16(v); return c.u;
}
__device__ __forceinline__ float gelu_f(float v) {
    return 0.5f * v * (1.f + erff(v * 0.70710678118f));
}

// ---------------- dtype detection ----------------
__global__ void k_detect(const u16* __restrict__ x, int n, int* __restrict__ flag) {
    __shared__ float smax[256];
    int tid = threadIdx.x;
    float m = 0.f;
    for (int i = tid; i < n; i += 256) {
        float v = fabsf(__uint_as_float(((u32)x[i]) << 16));
        if (v != v) v = 1e30f;
        m = fmaxf(m, v);
    }
    smax[tid] = m;
    __syncthreads();
    for (int s = 128; s > 0; s >>= 1) {
        if (tid < s) smax[tid] = fmaxf(smax[tid], smax[tid + s]);
        __syncthreads();
    }
    if (tid == 0) flag[0] = (smax[0] > 1e4f) ? 0 : 1;
}

// ---------------- merged x-input convert (x_a then x_b) — R4 version ----------------
__global__ void k_convb(const void* __restrict__ xa, const void* __restrict__ xb,
                        bf16* __restrict__ da, bf16* __restrict__ db,
                        const int* __restrict__ dflag) {
    int isb = dflag[0];
    int i = blockIdx.x * 256 + threadIdx.x;
    int na = NAn * 64;
    if (i < na) da[i] = isb ? ((const bf16*)xa)[i] : __float2bfloat16(((const float*)xa)[i]);
    else if (i < na + NBn * 32) {
        int j = i - na;
        db[j] = isb ? ((const bf16*)xb)[j] : __float2bfloat16(((const float*)xb)[j]);
    }
}

// ---------------- merged small weight prep (384 threads) ----------------
// blocks [0,2): bias_lin[768]; [2,205): wt transposes; [205,209): kqv bias (layout [k|v|q])
__global__ void k_prep_small(const void* __restrict__ lin_a_w, const void* __restrict__ lin_a_b,
                             const void* __restrict__ lin_b_w, const void* __restrict__ lin_b_b,
                             const void* __restrict__ a_lin_w, const void* __restrict__ a_lin_b,
                             const void* __restrict__ k_b, const void* __restrict__ q_b,
                             const void* __restrict__ v_b, const void* __restrict__ a_rel,
                             const void* __restrict__ m_rel, const void* __restrict__ p_rel,
                             float* __restrict__ bias_lin, bf16* __restrict__ wt_lin_a,
                             bf16* __restrict__ wt_lin_b, bf16* __restrict__ wt_alin,
                             float* __restrict__ b_kqv, const int* __restrict__ dflag) {
    int isb = dflag[0];
    int b = blockIdx.x, t = threadIdx.x;
    if (b < 2) {
        int i = b * 384 + t;
        if (i < 768) {
            float v = (i < 128) ? ldf(lin_a_b, i, isb)
                    : (i < 256) ? ldf(lin_b_b, i - 128, isb)
                                : ldf(a_lin_b, i - 256, isb);
            bias_lin[i] = v;
        }
    } else if (b < 205) {
        int e = (b - 2) * 384 + t;
        if (e < 8192) {            // wt_lin_a [128][64]
            int n = e >> 6, k = e & 63;
            wt_lin_a[e] = __float2bfloat16(ldf(lin_a_w, (size_t)k * 128 + n, isb));
        } else if (e < 12288) {    // wt_lin_b [128][32]
            int r = e - 8192; int n = r >> 5, k = r & 31;
            wt_lin_b[r] = __float2bfloat16(ldf(lin_b_w, (size_t)k * 128 + n, isb));
        } else if (e < 77824) {    // wt_alin [4][128][128]
            int r = e - 12288; int s = r >> 14, rem = r & 16383;
            int n = rem >> 7, k = rem & 127;
            wt_alin[r] = __float2bfloat16(ldf(a_lin_w, (size_t)s * 16384 + (size_t)k * 128 + n, isb));
        }
    } else {                       // kqv bias, lt = b-205; layout [k|v|q]; k scaled by LOG2E
        int lt = b - 205, j = t;
        float out;
        if (j < 128) {
            int h = j >> 5, e = j & 31;
            float s = ldf(p_rel, lt * Hh + h, isb) * INV_SQRT_D * LOG2E;
            float sum = 0.f;
            size_t kb0 = (size_t)lt * 128 + h * 32;
            size_t ar0 = ((size_t)lt * Hh + h) * 1024 + e;
            #pragma unroll
            for (int d = 0; d < 32; ++d) sum += ldf(k_b, kb0 + d, isb) * ldf(a_rel, ar0 + d * 32, isb);
            out = sum * s;
        } else if (j < 256) {
            int jj = j - 128; int h = jj >> 5, e = jj & 31;
            float sum = 0.f;
            size_t vb0 = (size_t)lt * 128 + h * 32;
            size_t mr0 = ((size_t)lt * Hh + h) * 1024 + e;
            #pragma unroll
            for (int d = 0; d < 32; ++d) sum += ldf(v_b, vb0 + d, isb) * ldf(m_rel, mr0 + d * 32, isb);
            out = sum;
        } else {
            out = ldf(q_b, (size_t)lt * 128 + (j - 256), isb);
        }
        b_kqv[(size_t)lt * 384 + j] = out;
    }
}

// ---------------- fused KQV weight prep: Wt[lt][384][128] bf16, layout [k|v|q] ----------------
__global__ void k_prep_kqv_w(const void* __restrict__ k_w, const void* __restrict__ q_w,
                             const void* __restrict__ v_w, const void* __restrict__ a_rel,
                             const void* __restrict__ m_rel, const void* __restrict__ p_rel,
                             bf16* __restrict__ Wt, const int* __restrict__ dflag) {
    int isb = dflag[0];
    int b = blockIdx.x;          // lt*128 + c (c = K index)
    int lt = b >> 7, c = b & 127;
    int j = threadIdx.x;         // 0..383 (N index)
    float out;
    if (j < 128) {               // k' scaled by p_rel/sqrt(D)*log2(e)
        int h = j >> 5, e = j & 31;
        float s = ldf(p_rel, lt * Hh + h, isb) * INV_SQRT_D * LOG2E;
        float sum = 0.f;
        size_t kw0 = ((size_t)lt * 128 + c) * 128 + h * 32;
        size_t ar0 = ((size_t)lt * Hh + h) * 1024 + e;
        #pragma unroll
        for (int d = 0; d < 32; ++d) sum += ldf(k_w, kw0 + d, isb) * ldf(a_rel, ar0 + d * 32, isb);
        out = sum * s;
    } else if (j < 256) {        // v'
        int jj = j - 128; int h = jj >> 5, e = jj & 31;
        float sum = 0.f;
        size_t vw0 = ((size_t)lt * 128 + c) * 128 + h * 32;
        size_t mr0 = ((size_t)lt * Hh + h) * 1024 + e;
        #pragma unroll
        for (int d = 0; d < 32; ++d) sum += ldf(v_w, vw0 + d, isb) * ldf(m_rel, mr0 + d * 32, isb);
        out = sum;
    } else {                     // q
        out = ldf(q_w, ((size_t)lt * 128 + c) * 128 + (j - 256), isb);
    }
    Wt[((size_t)lt * 384 + j) * 128 + c] = __float2bfloat16(out);
}

// ---------------- CSR build (both directions per launch) ----------------
__global__ void k_hist(const int* __restrict__ d0, const int* __restrict__ d1,
                       int* __restrict__ deg0, int* __restrict__ deg1) {
    int i = blockIdx.x * 256 + threadIdx.x;
    if (i >= NEe) return;
    if (blockIdx.y == 0) atomicAdd(&deg0[d0[i]], 1);
    else                 atomicAdd(&deg1[d1[i]], 1);
}

__global__ void k_scanA(const int* __restrict__ deg0, const int* __restrict__ deg1,
                        int* __restrict__ ex0, int* __restrict__ ex1,
                        int* __restrict__ bs0, int* __restrict__ bs1, int n) {
    const int* deg = blockIdx.y ? deg1 : deg0;
    int* excl = blockIdx.y ? ex1 : ex0;
    int* bsum = blockIdx.y ? bs1 : bs0;
    __shared__ int buf[256];
    int tid = threadIdx.x;
    int i = blockIdx.x * 256 + tid;
    int v = (i < n) ? deg[i] : 0;
    buf[tid] = v;
    __syncthreads();
    for (int off = 1; off < 256; off <<= 1) {
        int u = (tid >= off) ? buf[tid - off] : 0;
        __syncthreads();
        buf[tid] += u;
        __syncthreads();
    }
    int incl = buf[tid];
    if (i < n) excl[i] = incl - v;
    if (tid == 255) bsum[blockIdx.x] = incl;
}

__global__ void k_scanB(int* __restrict__ bs0, int* __restrict__ bs1, int nb) {
    int* bsum = blockIdx.x ? bs1 : bs0;
    __shared__ int buf[256];
    int tid = threadIdx.x;
    int v = (tid < nb) ? bsum[tid] : 0;
    buf[tid] = v;
    __syncthreads();
    for (int off = 1; off < 256; off <<= 1) {
        int u = (tid >= off) ? buf[tid - off] : 0;
        __syncthreads();
        buf[tid] += u;
        __syncthreads();
    }
    if (tid < nb) bsum[tid] = buf[tid] - v;
}

__global__ void k_scanC(int* __restrict__ rp0, int* __restrict__ rp1,
                        const int* __restrict__ bs0, const int* __restrict__ bs1,
                        int* __restrict__ cur0, int* __restrict__ cur1, int n) {
    int* rowptr = blockIdx.y ? rp1 : rp0;
    const int* bsum = blockIdx.y ? bs1 : bs0;
    int* cursor = blockIdx.y ? cur1 : cur0;
    int i = blockIdx.x * 256 + threadIdx.x;
    if (i < n) {
        int v = rowptr[i] + bsum[i >> 8];
        rowptr[i] = v;
        cursor[i] = v;
    }
    if (i == 0) rowptr[n] = NEe;
}

__global__ void k_scatter(const int* __restrict__ e0, const int* __restrict__ e1,
                          int* __restrict__ cur0, int* __restrict__ cur1,
                          int* __restrict__ cs0, int* __restrict__ cs1) {
    int i = blockIdx.x * 256 + threadIdx.x;
    if (i >= NEe) return;
    const int* e = blockIdx.y ? e1 : e0;
    int* cursor = blockIdx.y ? cur1 : cur0;
    int* csr = blockIdx.y ? cs1 : cs0;
    int d = e[NEe + i];
    int p = atomicAdd(&cursor[d], 1);
    csr[p] = e[i];
}

// ---------------- MFMA GEMM (R4 version, no ARAW) ----------------
// EPI: 0 = +bias ; 1 = relu ; 2 = skip blend s*(acc+bias)+(1-s)*oldx
template <int KK, int NSTEPS, int EPI>
__global__ __launch_bounds__(256) void k_mm2(const bf16* __restrict__ A0, const bf16* __restrict__ A1,
                                             int lda,
                                             const bf16* __restrict__ W0, const bf16* __restrict__ W1,
                                             const float* __restrict__ bias0, const float* __restrict__ bias1,
                                             bf16* __restrict__ out0, bf16* __restrict__ out1, int ldo,
                                             const bf16* __restrict__ old0, const bf16* __restrict__ old1,
                                             const void* __restrict__ skipp, int si0, int si1,
                                             const int* __restrict__ dflag) {
    constexpr int NK = KK / 32;
    int y = blockIdx.y;
    const bf16* A = y ? A1 : A0;
    const bf16* Wt = y ? W1 : W0;
    const float* bias = y ? bias1 : bias0;
    bf16* out = y ? out1 : out0;
    const bf16* oldx = y ? old1 : old0;
    int skip_idx = y ? si1 : si0;

    int tid = threadIdx.x;
    int w = tid >> 6, l = tid & 63;
    int r0 = blockIdx.x * 64 + (w & 1) * 32;
    int n0base = (w >> 1) * (NSTEPS * 32);
    int lr = l & 15, kb = l >> 4;

    s16x8 af[2][NK];
    #pragma unroll
    for (int mt = 0; mt < 2; ++mt)
        #pragma unroll
        for (int kf = 0; kf < NK; ++kf)
            af[mt][kf] = *(const s16x8*)(A + (size_t)(r0 + mt * 16 + lr) * lda + kf * 32 + kb * 8);

    s16x8 bfr[2][2][NK];
    #pragma unroll
    for (int nt = 0; nt < 2; ++nt)
        #pragma unroll
        for (int kf = 0; kf < NK; ++kf)
            bfr[0][nt][kf] = *(const s16x8*)(Wt + (size_t)(n0base + nt * 16 + lr) * KK + kf * 32 + kb * 8);

    float sg = 0.f;
    if (EPI == 2) {
        float sv = ldf(skipp, skip_idx, dflag[0]);
        sg = 1.f / (1.f + expf(-sv));
    }

    #pragma unroll
    for (int s = 0; s < NSTEPS; ++s) {
        int n0 = n0base + s * 32;
        if (s + 1 < NSTEPS) {
            #pragma unroll
            for (int nt = 0; nt < 2; ++nt)
                #pragma unroll
                for (int kf = 0; kf < NK; ++kf)
                    bfr[(s + 1) & 1][nt][kf] =
                        *(const s16x8*)(Wt + (size_t)(n0 + 32 + nt * 16 + lr) * KK + kf * 32 + kb * 8);
        }
        f32x4 acc[2][2] = {};
        #pragma unroll
        for (int kf = 0; kf < NK; ++kf)
            #pragma unroll
            for (int mt = 0; mt < 2; ++mt)
                #pragma unroll
                for (int nt = 0; nt < 2; ++nt)
                    acc[mt][nt] = __builtin_amdgcn_mfma_f32_16x16x32_bf16(
                        af[mt][kf], bfr[s & 1][nt][kf], acc[mt][nt], 0, 0, 0);
        #pragma unroll
        for (int mt = 0; mt < 2; ++mt)
            #pragma unroll
            for (int nt = 0; nt < 2; ++nt) {
                int col = n0 + nt * 16 + lr;
                float bv = bias[col];
                #pragma unroll
                for (int r = 0; r < 4; ++r) {
                    int row = r0 + mt * 16 + kb * 4 + r;
                    float o = acc[mt][nt][r] + bv;
                    if (EPI == 1) o = fmaxf(o, 0.f);
                    if (EPI == 2) o = sg * o + (1.f - sg) * bf2f(oldx[(size_t)row * 128 + col]);
                    out[(size_t)row * ldo + col] = __float2bfloat16(o);
                }
            }
    }
}

// ---------------- fused edge aggregation v2 (restructured; exp2f) ----------------
// One wave per dst node, 4 edges in flight (e-groups), 16B loads per lane.
// lane = eg*16 + hp; lane covers cols [hp*8, hp*8+8) (within head hp>>2).
// kqv layout [k|v|q]; k' pre-scaled by log2(e). Writes gelu(attn) to q-cols.
__global__ __launch_bounds__(256) void k_edge(const bf16* __restrict__ kv0, bf16* __restrict__ qm0,
                                              const int* __restrict__ rp0, const int* __restrict__ cs0,
                                              const bf16* __restrict__ kv1, bf16* __restrict__ qm1,
                                              const int* __restrict__ rp1, const int* __restrict__ cs1,
                                              int nblk0) {
    int dir = (blockIdx.x >= nblk0);
    int blk = dir ? (blockIdx.x - nblk0) : blockIdx.x;
    const bf16* kv = dir ? kv1 : kv0;
    bf16* qm = dir ? qm1 : qm0;
    const int* rowptr = dir ? rp1 : rp0;
    const int* csr = dir ? cs1 : cs0;

    int wave = threadIdx.x >> 6, lane = threadIdx.x & 63;
    int n = blk * 4 + wave;
    if (n >= NAn) return; // NAn == NBn
    int eg = lane >> 4, hp = lane & 15;
    bf16* qrow = qm + (size_t)n * 384 + 256;

    uint4 qv = *(const uint4*)(qrow + hp * 8);
    float qf0 = lo_bf(qv.x), qf1 = hi_bf(qv.x), qf2 = lo_bf(qv.y), qf3 = hi_bf(qv.y);
    float qf4 = lo_bf(qv.z), qf5 = hi_bf(qv.z), qf6 = lo_bf(qv.w), qf7 = hi_bf(qv.w);

    float den = 0.f;
    float a0 = 0.f, a1 = 0.f, a2 = 0.f, a3 = 0.f, a4 = 0.f, a5 = 0.f, a6 = 0.f, a7 = 0.f;
    int e0 = rowptr[n], e1 = rowptr[n + 1];
    for (int e = e0; e < e1; e += 4) {
        int ee = e + eg;
        bool valid = ee < e1;
        int sidx = csr[valid ? ee : e1 - 1];
        const bf16* row = kv + (size_t)sidx * 384;
        uint4 kw = *(const uint4*)(row + hp * 8);
        uint4 vw = *(const uint4*)(row + 128 + hp * 8);
        float part = qf0 * lo_bf(kw.x) + qf1 * hi_bf(kw.x)
                   + qf2 * lo_bf(kw.y) + qf3 * hi_bf(kw.y)
                   + qf4 * lo_bf(kw.z) + qf5 * hi_bf(kw.z)
                   + qf6 * lo_bf(kw.w) + qf7 * hi_bf(kw.w);
        part += __shfl_xor(part, 1);
        part += __shfl_xor(part, 2);
        float wgt = valid ? exp2f(part) : 0.f;
        den += wgt;
        a0 += wgt * lo_bf(vw.x); a1 += wgt * hi_bf(vw.x);
        a2 += wgt * lo_bf(vw.y); a3 += wgt * hi_bf(vw.y);
        a4 += wgt * lo_bf(vw.z); a5 += wgt * hi_bf(vw.z);
        a6 += wgt * lo_bf(vw.w); a7 += wgt * hi_bf(vw.w);
    }
    // cross-e-group reduction (xor 16, 32): full sums in every lane
    #pragma unroll
    for (int m = 16; m <= 32; m <<= 1) {
        den += __shfl_xor(den, m);
        a0 += __shfl_xor(a0, m); a1 += __shfl_xor(a1, m);
        a2 += __shfl_xor(a2, m); a3 += __shfl_xor(a3, m);
        a4 += __shfl_xor(a4, m); a5 += __shfl_xor(a5, m);
        a6 += __shfl_xor(a6, m); a7 += __shfl_xor(a7, m);
    }
    float inv = 1.f / (den + 1e-16f);
    // lane with e-group eg writes cols hp*8 + {2eg, 2eg+1}
    float s0 = (eg == 0) ? a0 : (eg == 1) ? a2 : (eg == 2) ? a4 : a6;
    float s1 = (eg == 0) ? a1 : (eg == 1) ? a3 : (eg == 2) ? a5 : a7;
    float g0 = gelu_f(s0 * inv);
    float g1 = gelu_f(s1 * inv);
    u32 pk = (u32)f2bu(g0) | ((u32)f2bu(g1) << 16);
    *(u32*)(qrow + hp * 8 + 2 * eg) = pk;
}

// ---------------- final output (adaptive dtype) — R4 version ----------------
__global__ void k_out(const bf16* __restrict__ xa, const bf16* __restrict__ xb,
                      void* __restrict__ out, int n_each, const int* __restrict__ dflag) {
    int isb = dflag[0];
    int i = blockIdx.x * blockDim.x + threadIdx.x;
    if (i >= 2 * n_each) return;
    bf16 v = (i < n_each) ? xa[i] : xb[i - n_each];
    if (isb) ((bf16*)out)[i] = v;
    else     ((float*)out)[i] = bf2f(v);
}

extern "C" void kernel_launch(void* const* d_in, const int* in_sizes, int n_in,
                              void* d_out, int out_size, void* d_ws, size_t ws_size,
                              hipStream_t stream) {
    const void* x_a     = d_in[0];
    const void* x_b     = d_in[1];
    const int*  edge_ab = (const int*)d_in[2];
    const int*  edge_ba = (const int*)d_in[3];
    const void* lin_a_w = d_in[4];
    const void* lin_a_b = d_in[5];
    const void* lin_b_w = d_in[6];
    const void* lin_b_b = d_in[7];
    const void* k_w     = d_in[8];
    const void* k_b     = d_in[9];
    const void* q_w     = d_in[10];
    const void* q_b     = d_in[11];
    const void* v_w     = d_in[12];
    const void* v_b     = d_in[13];
    const void* a_rel   = d_in[14];
    const void* m_rel   = d_in[15];
    const void* p_rel   = d_in[16];
    const void* a_lin_w = d_in[17];
    const void* a_lin_b = d_in[18];
    const void* skip    = d_in[19];

    // -------- workspace layout --------
    char* p = (char*)d_ws;
    auto falloc = [&](size_t n) { float* r = (float*)p; p += n * sizeof(float); return r; };
    float* bias_lin = falloc(768);       // [lin_a_b | lin_b_b | a_lin_b(512)]
    float* b_kqv    = falloc(4 * 384);
    auto halloc = [&](size_t n) { bf16* r = (bf16*)p; p += n * sizeof(bf16); return r; };
    bf16* x_a_bf   = halloc((size_t)NAn * 64);
    bf16* x_b_bf   = halloc((size_t)NBn * 32);
    bf16* xa_bf    = halloc((size_t)NAn * Cc);
    bf16* xb_bf    = halloc((size_t)NBn * Cc);
    bf16* kqv_a    = halloc((size_t)NAn * 384);
    bf16* kqv_b    = halloc((size_t)NBn * 384);
    bf16* wt_lin_a = halloc(128 * 64);
    bf16* wt_lin_b = halloc(128 * 32);
    bf16* wt_kqv   = halloc(4 * 384 * 128);
    bf16* wt_alin  = halloc(4 * 128 * 128);
    auto ialloc = [&](size_t n) { int* r = (int*)p; p += n * sizeof(int); return r; };
    int* dflag     = ialloc(4);
    int* rowptr_ab = ialloc(NBn + 1);
    int* rowptr_ba = ialloc(NAn + 1);
    int* deg_ab    = ialloc(NBn);       // adjacent -> single memset
    int* deg_ba    = ialloc(NAn);
    int* cursor_ab = ialloc(NBn);
    int* cursor_ba = ialloc(NAn);
    int* bsum_ab   = ialloc(256);
    int* bsum_ba   = ialloc(256);
    int* csr_ab    = ialloc(NEe);
    int* csr_ba    = ialloc(NEe);

    // -------- dtype detection --------
    k_detect<<<1, 256, 0, stream>>>((const u16*)x_a, 8192, dflag);

    // -------- weight prep (2 launches) --------
    k_prep_small<<<209, 384, 0, stream>>>(lin_a_w, lin_a_b, lin_b_w, lin_b_b, a_lin_w, a_lin_b,
                                          k_b, q_b, v_b, a_rel, m_rel, p_rel,
                                          bias_lin, wt_lin_a, wt_lin_b, wt_alin, b_kqv, dflag);
    k_prep_kqv_w<<<512, 384, 0, stream>>>(k_w, q_w, v_w, a_rel, m_rel, p_rel, wt_kqv, dflag);

    // -------- x inputs -> bf16 (always copies; R4 version) --------
    k_convb<<<(NAn * 64 + NBn * 32 + 255) / 256, 256, 0, stream>>>(x_a, x_b, x_a_bf, x_b_bf, dflag);

    // -------- CSR build, both directions --------
    hipMemsetAsync(deg_ab, 0, 2 * NAn * sizeof(int), stream);
    dim3 eg((NEe + 255) / 256, 2);
    k_hist<<<eg, 256, 0, stream>>>(edge_ab + NEe, edge_ba + NEe, deg_ab, deg_ba);
    int nblk = (NBn + 255) / 256; // 157
    k_scanA<<<dim3(nblk, 2), 256, 0, stream>>>(deg_ab, deg_ba, rowptr_ab, rowptr_ba,
                                               bsum_ab, bsum_ba, NBn);
    k_scanB<<<2, 256, 0, stream>>>(bsum_ab, bsum_ba, nblk);
    k_scanC<<<dim3(nblk, 2), 256, 0, stream>>>(rowptr_ab, rowptr_ba, bsum_ab, bsum_ba,
                                               cursor_ab, cursor_ba, NBn);
    k_scatter<<<eg, 256, 0, stream>>>(edge_ab, edge_ba, cursor_ab, cursor_ba, csr_ab, csr_ba);

    // -------- input linears + relu (from converted buffers; R4 version) --------
    k_mm2<64, 2, 1><<<dim3(NAn / 64, 1), 256, 0, stream>>>(
        x_a_bf, x_a_bf, 64, wt_lin_a, wt_lin_a, bias_lin, bias_lin,
        xa_bf, xa_bf, 128, nullptr, nullptr, nullptr, 0, 0, dflag);
    k_mm2<32, 2, 1><<<dim3(NBn / 64, 1), 256, 0, stream>>>(
        x_b_bf, x_b_bf, 32, wt_lin_b, wt_lin_b, bias_lin + 128, bias_lin + 128,
        xb_bf, xb_bf, 128, nullptr, nullptr, nullptr, 0, 0, dflag);

    // -------- layers --------
    for (int l = 0; l < Ll; ++l) {
        int lt0 = l * 2 + 0, lt1 = l * 2 + 1;
        k_mm2<128, 6, 0><<<dim3(NAn / 64, 2), 256, 0, stream>>>(
            xa_bf, xb_bf, 128,
            wt_kqv + (size_t)lt0 * 384 * 128, wt_kqv + (size_t)lt1 * 384 * 128,
            b_kqv + (size_t)lt0 * 384, b_kqv + (size_t)lt1 * 384,
            kqv_a, kqv_b, 384, nullptr, nullptr, nullptr, 0, 0, dflag);
        int nblk0 = (NBn + 3) / 4;
        k_edge<<<nblk0 + (NAn + 3) / 4, 256, 0, stream>>>(
            kqv_a, kqv_b, rowptr_ab, csr_ab,
            kqv_b, kqv_a, rowptr_ba, csr_ba, nblk0);
        // a_lin + skip blend (in-place update of xa_bf/xb_bf; R4 version)
        k_mm2<128, 2, 2><<<dim3(NAn / 64, 2), 256, 0, stream>>>(
            kqv_a + 256, kqv_b + 256, 384,
            wt_alin + (size_t)lt0 * 128 * 128, wt_alin + (size_t)lt1 * 128 * 128,
            bias_lin + 256 + (size_t)lt0 * 128, bias_lin + 256 + (size_t)lt1 * 128,
            xa_bf, xb_bf, 128, xa_bf, xb_bf, skip, lt0, lt1, dflag);
    }

    // -------- output (R4 version) --------
    int n_each = NAn * Cc;
    k_out<<<(2 * n_each + 255) / 256, 256, 0, stream>>>(xa_bf, xb_bf, d_out, n_each, dflag);
}

// Round 8
// 307.931 us; speedup vs baseline: 2.3829x; 1.0419x over previous
//
#include <hip/hip_runtime.h>
#include <hip/hip_bf16.h>
#include <math.h>

#define NAn 40000
#define NBn 40000
#define NEe 250000
#define Cc 128
#define Hh 4
#define Ll 2
static constexpr float INV_SQRT_D = 0.17677669529663687f; // 1/sqrt(32)
static constexpr float LOG2E = 1.4426950408889634f;

typedef __hip_bfloat16 bf16;
typedef unsigned short u16;
typedef unsigned int u32;
typedef short s16x8 __attribute__((ext_vector_type(8)));
typedef float f32x4 __attribute__((ext_vector_type(4)));
typedef float f32x2 __attribute__((ext_vector_type(2)));
typedef __bf16 bf16x2 __attribute__((ext_vector_type(2)));

#if defined(__has_builtin)
#  if __has_builtin(__builtin_amdgcn_fdot2_f32_bf16)
#    define HAVE_DOT2 1
#  endif
#endif
#ifndef HAVE_DOT2
#  define HAVE_DOT2 0
#endif

__device__ __forceinline__ float bf2f(bf16 x) { return __bfloat162float(x); }
__device__ __forceinline__ float lo_bf(u32 w) { return __uint_as_float(w << 16); }
__device__ __forceinline__ float hi_bf(u32 w) { return __uint_as_float(w & 0xffff0000u); }
__device__ __forceinline__ float ldf(const void* p, size_t i, int isb) {
    return isb ? bf2f(((const bf16*)p)[i]) : ((const float*)p)[i];
}
__device__ __forceinline__ u16 f2bu(float v) {
    union { bf16 b; u16 u; } c; c.b = __float2bfloat16(v); return c.u;
}
__device__ __forceinline__ float gelu_f(float v) {
    return 0.5f * v * (1.f + erff(v * 0.70710678118f));
}
__device__ __forceinline__ bf16x2 as_b2(u32 w) {
    union { u32 u; bf16x2 v; } c; c.u = w; return c.v;
}

// ---------------- dtype detection ----------------
__global__ void k_detect(const u16* __restrict__ x, int n, int* __restrict__ flag) {
    __shared__ float smax[256];
    int tid = threadIdx.x;
    float m = 0.f;
    for (int i = tid; i < n; i += 256) {
        float v = fabsf(__uint_as_float(((u32)x[i]) << 16));
        if (v != v) v = 1e30f;
        m = fmaxf(m, v);
    }
    smax[tid] = m;
    __syncthreads();
    for (int s = 128; s > 0; s >>= 1) {
        if (tid < s) smax[tid] = fmaxf(smax[tid], smax[tid + s]);
        __syncthreads();
    }
    if (tid == 0) flag[0] = (smax[0] > 1e4f) ? 0 : 1;
}

// ---------------- merged x-input convert (x_a then x_b) — R4/R7 version ----------------
__global__ void k_convb(const void* __restrict__ xa, const void* __restrict__ xb,
                        bf16* __restrict__ da, bf16* __restrict__ db,
                        const int* __restrict__ dflag) {
    int isb = dflag[0];
    int i = blockIdx.x * 256 + threadIdx.x;
    int na = NAn * 64;
    if (i < na) da[i] = isb ? ((const bf16*)xa)[i] : __float2bfloat16(((const float*)xa)[i]);
    else if (i < na + NBn * 32) {
        int j = i - na;
        db[j] = isb ? ((const bf16*)xb)[j] : __float2bfloat16(((const float*)xb)[j]);
    }
}

// ---------------- merged small weight prep (384 threads) ----------------
// blocks [0,2): bias_lin[768]; [2,205): wt transposes; [205,209): kqv bias (layout [k|v|q])
__global__ void k_prep_small(const void* __restrict__ lin_a_w, const void* __restrict__ lin_a_b,
                             const void* __restrict__ lin_b_w, const void* __restrict__ lin_b_b,
                             const void* __restrict__ a_lin_w, const void* __restrict__ a_lin_b,
                             const void* __restrict__ k_b, const void* __restrict__ q_b,
                             const void* __restrict__ v_b, const void* __restrict__ a_rel,
                             const void* __restrict__ m_rel, const void* __restrict__ p_rel,
                             float* __restrict__ bias_lin, bf16* __restrict__ wt_lin_a,
                             bf16* __restrict__ wt_lin_b, bf16* __restrict__ wt_alin,
                             float* __restrict__ b_kqv, const int* __restrict__ dflag) {
    int isb = dflag[0];
    int b = blockIdx.x, t = threadIdx.x;
    if (b < 2) {
        int i = b * 384 + t;
        if (i < 768) {
            float v = (i < 128) ? ldf(lin_a_b, i, isb)
                    : (i < 256) ? ldf(lin_b_b, i - 128, isb)
                                : ldf(a_lin_b, i - 256, isb);
            bias_lin[i] = v;
        }
    } else if (b < 205) {
        int e = (b - 2) * 384 + t;
        if (e < 8192) {            // wt_lin_a [128][64]
            int n = e >> 6, k = e & 63;
            wt_lin_a[e] = __float2bfloat16(ldf(lin_a_w, (size_t)k * 128 + n, isb));
        } else if (e < 12288) {    // wt_lin_b [128][32]
            int r = e - 8192; int n = r >> 5, k = r & 31;
            wt_lin_b[r] = __float2bfloat16(ldf(lin_b_w, (size_t)k * 128 + n, isb));
        } else if (e < 77824) {    // wt_alin [4][128][128]
            int r = e - 12288; int s = r >> 14, rem = r & 16383;
            int n = rem >> 7, k = rem & 127;
            wt_alin[r] = __float2bfloat16(ldf(a_lin_w, (size_t)s * 16384 + (size_t)k * 128 + n, isb));
        }
    } else {                       // kqv bias, lt = b-205; layout [k|v|q]; k scaled by LOG2E
        int lt = b - 205, j = t;
        float out;
        if (j < 128) {
            int h = j >> 5, e = j & 31;
            float s = ldf(p_rel, lt * Hh + h, isb) * INV_SQRT_D * LOG2E;
            float sum = 0.f;
            size_t kb0 = (size_t)lt * 128 + h * 32;
            size_t ar0 = ((size_t)lt * Hh + h) * 1024 + e;
            #pragma unroll
            for (int d = 0; d < 32; ++d) sum += ldf(k_b, kb0 + d, isb) * ldf(a_rel, ar0 + d * 32, isb);
            out = sum * s;
        } else if (j < 256) {
            int jj = j - 128; int h = jj >> 5, e = jj & 31;
            float sum = 0.f;
            size_t vb0 = (size_t)lt * 128 + h * 32;
            size_t mr0 = ((size_t)lt * Hh + h) * 1024 + e;
            #pragma unroll
            for (int d = 0; d < 32; ++d) sum += ldf(v_b, vb0 + d, isb) * ldf(m_rel, mr0 + d * 32, isb);
            out = sum;
        } else {
            out = ldf(q_b, (size_t)lt * 128 + (j - 256), isb);
        }
        b_kqv[(size_t)lt * 384 + j] = out;
    }
}

// ---------------- fused KQV weight prep: Wt[lt][384][128] bf16, layout [k|v|q] ----------------
__global__ void k_prep_kqv_w(const void* __restrict__ k_w, const void* __restrict__ q_w,
                             const void* __restrict__ v_w, const void* __restrict__ a_rel,
                             const void* __restrict__ m_rel, const void* __restrict__ p_rel,
                             bf16* __restrict__ Wt, const int* __restrict__ dflag) {
    int isb = dflag[0];
    int b = blockIdx.x;          // lt*128 + c (c = K index)
    int lt = b >> 7, c = b & 127;
    int j = threadIdx.x;         // 0..383 (N index)
    float out;
    if (j < 128) {               // k' scaled by p_rel/sqrt(D)*log2(e)
        int h = j >> 5, e = j & 31;
        float s = ldf(p_rel, lt * Hh + h, isb) * INV_SQRT_D * LOG2E;
        float sum = 0.f;
        size_t kw0 = ((size_t)lt * 128 + c) * 128 + h * 32;
        size_t ar0 = ((size_t)lt * Hh + h) * 1024 + e;
        #pragma unroll
        for (int d = 0; d < 32; ++d) sum += ldf(k_w, kw0 + d, isb) * ldf(a_rel, ar0 + d * 32, isb);
        out = sum * s;
    } else if (j < 256) {        // v'
        int jj = j - 128; int h = jj >> 5, e = jj & 31;
        float sum = 0.f;
        size_t vw0 = ((size_t)lt * 128 + c) * 128 + h * 32;
        size_t mr0 = ((size_t)lt * Hh + h) * 1024 + e;
        #pragma unroll
        for (int d = 0; d < 32; ++d) sum += ldf(v_w, vw0 + d, isb) * ldf(m_rel, mr0 + d * 32, isb);
        out = sum;
    } else {                     // q
        out = ldf(q_w, ((size_t)lt * 128 + c) * 128 + (j - 256), isb);
    }
    Wt[((size_t)lt * 384 + j) * 128 + c] = __float2bfloat16(out);
}

// ---------------- CSR build (both directions per launch) ----------------
__global__ void k_hist(const int* __restrict__ d0, const int* __restrict__ d1,
                       int* __restrict__ deg0, int* __restrict__ deg1) {
    int i = blockIdx.x * 256 + threadIdx.x;
    if (i >= NEe) return;
    if (blockIdx.y == 0) atomicAdd(&deg0[d0[i]], 1);
    else                 atomicAdd(&deg1[d1[i]], 1);
}

__global__ void k_scanA(const int* __restrict__ deg0, const int* __restrict__ deg1,
                        int* __restrict__ ex0, int* __restrict__ ex1,
                        int* __restrict__ bs0, int* __restrict__ bs1, int n) {
    const int* deg = blockIdx.y ? deg1 : deg0;
    int* excl = blockIdx.y ? ex1 : ex0;
    int* bsum = blockIdx.y ? bs1 : bs0;
    __shared__ int buf[256];
    int tid = threadIdx.x;
    int i = blockIdx.x * 256 + tid;
    int v = (i < n) ? deg[i] : 0;
    buf[tid] = v;
    __syncthreads();
    for (int off = 1; off < 256; off <<= 1) {
        int u = (tid >= off) ? buf[tid - off] : 0;
        __syncthreads();
        buf[tid] += u;
        __syncthreads();
    }
    int incl = buf[tid];
    if (i < n) excl[i] = incl - v;
    if (tid == 255) bsum[blockIdx.x] = incl;
}

__global__ void k_scanB(int* __restrict__ bs0, int* __restrict__ bs1, int nb) {
    int* bsum = blockIdx.x ? bs1 : bs0;
    __shared__ int buf[256];
    int tid = threadIdx.x;
    int v = (tid < nb) ? bsum[tid] : 0;
    buf[tid] = v;
    __syncthreads();
    for (int off = 1; off < 256; off <<= 1) {
        int u = (tid >= off) ? buf[tid - off] : 0;
        __syncthreads();
        buf[tid] += u;
        __syncthreads();
    }
    if (tid < nb) bsum[tid] = buf[tid] - v;
}

__global__ void k_scanC(int* __restrict__ rp0, int* __restrict__ rp1,
                        const int* __restrict__ bs0, const int* __restrict__ bs1,
                        int* __restrict__ cur0, int* __restrict__ cur1, int n) {
    int* rowptr = blockIdx.y ? rp1 : rp0;
    const int* bsum = blockIdx.y ? bs1 : bs0;
    int* cursor = blockIdx.y ? cur1 : cur0;
    int i = blockIdx.x * 256 + threadIdx.x;
    if (i < n) {
        int v = rowptr[i] + bsum[i >> 8];
        rowptr[i] = v;
        cursor[i] = v;
    }
    if (i == 0) rowptr[n] = NEe;
}

__global__ void k_scatter(const int* __restrict__ e0, const int* __restrict__ e1,
                          int* __restrict__ cur0, int* __restrict__ cur1,
                          int* __restrict__ cs0, int* __restrict__ cs1) {
    int i = blockIdx.x * 256 + threadIdx.x;
    if (i >= NEe) return;
    const int* e = blockIdx.y ? e1 : e0;
    int* cursor = blockIdx.y ? cur1 : cur0;
    int* csr = blockIdx.y ? cs1 : cs0;
    int d = e[NEe + i];
    int p = atomicAdd(&cursor[d], 1);
    csr[p] = e[i];
}

// ---------------- MFMA GEMM (unchanged from R7) ----------------
// EPI: 0 = +bias ; 1 = relu ; 2 = skip blend s*(acc+bias)+(1-s)*oldx
template <int KK, int NSTEPS, int EPI>
__global__ __launch_bounds__(256) void k_mm2(const bf16* __restrict__ A0, const bf16* __restrict__ A1,
                                             int lda,
                                             const bf16* __restrict__ W0, const bf16* __restrict__ W1,
                                             const float* __restrict__ bias0, const float* __restrict__ bias1,
                                             bf16* __restrict__ out0, bf16* __restrict__ out1, int ldo,
                                             const bf16* __restrict__ old0, const bf16* __restrict__ old1,
                                             const void* __restrict__ skipp, int si0, int si1,
                                             const int* __restrict__ dflag) {
    constexpr int NK = KK / 32;
    int y = blockIdx.y;
    const bf16* A = y ? A1 : A0;
    const bf16* Wt = y ? W1 : W0;
    const float* bias = y ? bias1 : bias0;
    bf16* out = y ? out1 : out0;
    const bf16* oldx = y ? old1 : old0;
    int skip_idx = y ? si1 : si0;

    int tid = threadIdx.x;
    int w = tid >> 6, l = tid & 63;
    int r0 = blockIdx.x * 64 + (w & 1) * 32;
    int n0base = (w >> 1) * (NSTEPS * 32);
    int lr = l & 15, kb = l >> 4;

    s16x8 af[2][NK];
    #pragma unroll
    for (int mt = 0; mt < 2; ++mt)
        #pragma unroll
        for (int kf = 0; kf < NK; ++kf)
            af[mt][kf] = *(const s16x8*)(A + (size_t)(r0 + mt * 16 + lr) * lda + kf * 32 + kb * 8);

    s16x8 bfr[2][2][NK];
    #pragma unroll
    for (int nt = 0; nt < 2; ++nt)
        #pragma unroll
        for (int kf = 0; kf < NK; ++kf)
            bfr[0][nt][kf] = *(const s16x8*)(Wt + (size_t)(n0base + nt * 16 + lr) * KK + kf * 32 + kb * 8);

    float sg = 0.f;
    if (EPI == 2) {
        float sv = ldf(skipp, skip_idx, dflag[0]);
        sg = 1.f / (1.f + expf(-sv));
    }

    #pragma unroll
    for (int s = 0; s < NSTEPS; ++s) {
        int n0 = n0base + s * 32;
        if (s + 1 < NSTEPS) {
            #pragma unroll
            for (int nt = 0; nt < 2; ++nt)
                #pragma unroll
                for (int kf = 0; kf < NK; ++kf)
                    bfr[(s + 1) & 1][nt][kf] =
                        *(const s16x8*)(Wt + (size_t)(n0 + 32 + nt * 16 + lr) * KK + kf * 32 + kb * 8);
        }
        f32x4 acc[2][2] = {};
        #pragma unroll
        for (int kf = 0; kf < NK; ++kf)
            #pragma unroll
            for (int mt = 0; mt < 2; ++mt)
                #pragma unroll
                for (int nt = 0; nt < 2; ++nt)
                    acc[mt][nt] = __builtin_amdgcn_mfma_f32_16x16x32_bf16(
                        af[mt][kf], bfr[s & 1][nt][kf], acc[mt][nt], 0, 0, 0);
        #pragma unroll
        for (int mt = 0; mt < 2; ++mt)
            #pragma unroll
            for (int nt = 0; nt < 2; ++nt) {
                int col = n0 + nt * 16 + lr;
                float bv = bias[col];
                #pragma unroll
                for (int r = 0; r < 4; ++r) {
                    int row = r0 + mt * 16 + kb * 4 + r;
                    float o = acc[mt][nt][r] + bv;
                    if (EPI == 1) o = fmaxf(o, 0.f);
                    if (EPI == 2) o = sg * o + (1.f - sg) * bf2f(oldx[(size_t)row * 128 + col]);
                    out[(size_t)row * ldo + col] = __float2bfloat16(o);
                }
            }
    }
}

// ---------------- fused edge aggregation v3: dot2 + csr prefetch + packed acc ----------------
// One wave per dst node, 4 edges in flight (e-groups), 16B loads per lane.
// lane = eg*16 + hp; lane covers cols [hp*8, hp*8+8).
// kqv layout [k|v|q]; k' pre-scaled by log2(e). Writes gelu(attn) to q-cols.
__global__ __launch_bounds__(256) void k_edge(const bf16* __restrict__ kv0, bf16* __restrict__ qm0,
                                              const int* __restrict__ rp0, const int* __restrict__ cs0,
                                              const bf16* __restrict__ kv1, bf16* __restrict__ qm1,
                                              const int* __restrict__ rp1, const int* __restrict__ cs1,
                                              int nblk0) {
    int dir = (blockIdx.x >= nblk0);
    int blk = dir ? (blockIdx.x - nblk0) : blockIdx.x;
    const bf16* kv = dir ? kv1 : kv0;
    bf16* qm = dir ? qm1 : qm0;
    const int* rowptr = dir ? rp1 : rp0;
    const int* csr = dir ? cs1 : cs0;

    int wave = threadIdx.x >> 6, lane = threadIdx.x & 63;
    int n = blk * 4 + wave;
    if (n >= NAn) return; // NAn == NBn
    int eg = lane >> 4, hp = lane & 15;
    bf16* qrow = qm + (size_t)n * 384 + 256;

    uint4 qv = *(const uint4*)(qrow + hp * 8);
#if HAVE_DOT2
    bf16x2 qb0 = as_b2(qv.x), qb1 = as_b2(qv.y), qb2 = as_b2(qv.z), qb3 = as_b2(qv.w);
#else
    float qf0 = lo_bf(qv.x), qf1 = hi_bf(qv.x), qf2 = lo_bf(qv.y), qf3 = hi_bf(qv.y);
    float qf4 = lo_bf(qv.z), qf5 = hi_bf(qv.z), qf6 = lo_bf(qv.w), qf7 = hi_bf(qv.w);
#endif

    float den = 0.f;
    f32x2 a01 = {0.f, 0.f}, a23 = {0.f, 0.f}, a45 = {0.f, 0.f}, a67 = {0.f, 0.f};
    int e0 = rowptr[n], e1 = rowptr[n + 1];
    // prefetch first csr index for this lane's e-group
    int sidx_n = 0;
    {
        int ee = e0 + eg;
        if (ee < e1) sidx_n = csr[ee];
    }
    for (int e = e0; e < e1; e += 4) {
        int sidx = sidx_n;
        bool valid = (e + eg) < e1;
        int en = e + 4 + eg;
        if (en < e1) sidx_n = csr[en];     // prefetch next iteration's index
        const bf16* row = kv + (size_t)sidx * 384;
        uint4 kw = *(const uint4*)(row + hp * 8);
        uint4 vw = *(const uint4*)(row + 128 + hp * 8);
#if HAVE_DOT2
        float part = __builtin_amdgcn_fdot2_f32_bf16(as_b2(kw.x), qb0, 0.f, false);
        part = __builtin_amdgcn_fdot2_f32_bf16(as_b2(kw.y), qb1, part, false);
        part = __builtin_amdgcn_fdot2_f32_bf16(as_b2(kw.z), qb2, part, false);
        part = __builtin_amdgcn_fdot2_f32_bf16(as_b2(kw.w), qb3, part, false);
#else
        float part = qf0 * lo_bf(kw.x) + qf1 * hi_bf(kw.x)
                   + qf2 * lo_bf(kw.y) + qf3 * hi_bf(kw.y)
                   + qf4 * lo_bf(kw.z) + qf5 * hi_bf(kw.z)
                   + qf6 * lo_bf(kw.w) + qf7 * hi_bf(kw.w);
#endif
        part += __shfl_xor(part, 1);
        part += __shfl_xor(part, 2);
        float wgt = valid ? exp2f(part) : 0.f;
        den += wgt;
        f32x2 w2; w2[0] = wgt; w2[1] = wgt;
        f32x2 t;
        t[0] = lo_bf(vw.x); t[1] = hi_bf(vw.x); a01 += w2 * t;
        t[0] = lo_bf(vw.y); t[1] = hi_bf(vw.y); a23 += w2 * t;
        t[0] = lo_bf(vw.z); t[1] = hi_bf(vw.z); a45 += w2 * t;
        t[0] = lo_bf(vw.w); t[1] = hi_bf(vw.w); a67 += w2 * t;
    }
    // cross-e-group reduction (xor 16, 32): full sums in every lane
    #pragma unroll
    for (int m = 16; m <= 32; m <<= 1) {
        den += __shfl_xor(den, m);
        a01[0] += __shfl_xor(a01[0], m); a01[1] += __shfl_xor(a01[1], m);
        a23[0] += __shfl_xor(a23[0], m); a23[1] += __shfl_xor(a23[1], m);
        a45[0] += __shfl_xor(a45[0], m); a45[1] += __shfl_xor(a45[1], m);
        a67[0] += __shfl_xor(a67[0], m); a67[1] += __shfl_xor(a67[1], m);
    }
    float inv = 1.f / (den + 1e-16f);
    // lane with e-group eg writes cols hp*8 + {2eg, 2eg+1}
    float s0 = (eg == 0) ? a01[0] : (eg == 1) ? a23[0] : (eg == 2) ? a45[0] : a67[0];
    float s1 = (eg == 0) ? a01[1] : (eg == 1) ? a23[1] : (eg == 2) ? a45[1] : a67[1];
    float g0 = gelu_f(s0 * inv);
    float g1 = gelu_f(s1 * inv);
    u32 pk = (u32)f2bu(g0) | ((u32)f2bu(g1) << 16);
    *(u32*)(qrow + hp * 8 + 2 * eg) = pk;
}

// ---------------- final output (adaptive dtype), vectorized 8 elems/thread ----------------
__global__ void k_out(const bf16* __restrict__ xa, const bf16* __restrict__ xb,
                      void* __restrict__ out, const int* __restrict__ dflag) {
    int isb = dflag[0];
    int i = blockIdx.x * 256 + threadIdx.x;   // 8-elem group index
    int na8 = NAn * Cc / 8;
    if (i >= 2 * na8) return;
    const bf16* src = (i < na8) ? xa : xb;
    int j = (i < na8) ? i : i - na8;
    uint4 v = *(const uint4*)(src + (size_t)j * 8);
    if (isb) {
        ((uint4*)out)[i] = v;
    } else {
        float4 f0 = make_float4(lo_bf(v.x), hi_bf(v.x), lo_bf(v.y), hi_bf(v.y));
        float4 f1 = make_float4(lo_bf(v.z), hi_bf(v.z), lo_bf(v.w), hi_bf(v.w));
        ((float4*)out)[i * 2] = f0;
        ((float4*)out)[i * 2 + 1] = f1;
    }
}

extern "C" void kernel_launch(void* const* d_in, const int* in_sizes, int n_in,
                              void* d_out, int out_size, void* d_ws, size_t ws_size,
                              hipStream_t stream) {
    const void* x_a     = d_in[0];
    const void* x_b     = d_in[1];
    const int*  edge_ab = (const int*)d_in[2];
    const int*  edge_ba = (const int*)d_in[3];
    const void* lin_a_w = d_in[4];
    const void* lin_a_b = d_in[5];
    const void* lin_b_w = d_in[6];
    const void* lin_b_b = d_in[7];
    const void* k_w     = d_in[8];
    const void* k_b     = d_in[9];
    const void* q_w     = d_in[10];
    const void* q_b     = d_in[11];
    const void* v_w     = d_in[12];
    const void* v_b     = d_in[13];
    const void* a_rel   = d_in[14];
    const void* m_rel   = d_in[15];
    const void* p_rel   = d_in[16];
    const void* a_lin_w = d_in[17];
    const void* a_lin_b = d_in[18];
    const void* skip    = d_in[19];

    // -------- workspace layout --------
    char* p = (char*)d_ws;
    auto falloc = [&](size_t n) { float* r = (float*)p; p += n * sizeof(float); return r; };
    float* bias_lin = falloc(768);       // [lin_a_b | lin_b_b | a_lin_b(512)]
    float* b_kqv    = falloc(4 * 384);
    auto halloc = [&](size_t n) { bf16* r = (bf16*)p; p += n * sizeof(bf16); return r; };
    bf16* x_a_bf   = halloc((size_t)NAn * 64);
    bf16* x_b_bf   = halloc((size_t)NBn * 32);
    bf16* xa_bf    = halloc((size_t)NAn * Cc);
    bf16* xb_bf    = halloc((size_t)NBn * Cc);
    bf16* kqv_a    = halloc((size_t)NAn * 384);
    bf16* kqv_b    = halloc((size_t)NBn * 384);
    bf16* wt_lin_a = halloc(128 * 64);
    bf16* wt_lin_b = halloc(128 * 32);
    bf16* wt_kqv   = halloc(4 * 384 * 128);
    bf16* wt_alin  = halloc(4 * 128 * 128);
    auto ialloc = [&](size_t n) { int* r = (int*)p; p += n * sizeof(int); return r; };
    int* dflag     = ialloc(4);
    int* rowptr_ab = ialloc(NBn + 1);
    int* rowptr_ba = ialloc(NAn + 1);
    int* deg_ab    = ialloc(NBn);       // adjacent -> single memset
    int* deg_ba    = ialloc(NAn);
    int* cursor_ab = ialloc(NBn);
    int* cursor_ba = ialloc(NAn);
    int* bsum_ab   = ialloc(256);
    int* bsum_ba   = ialloc(256);
    int* csr_ab    = ialloc(NEe);
    int* csr_ba    = ialloc(NEe);

    // -------- dtype detection --------
    k_detect<<<1, 256, 0, stream>>>((const u16*)x_a, 8192, dflag);

    // -------- weight prep (2 launches) --------
    k_prep_small<<<209, 384, 0, stream>>>(lin_a_w, lin_a_b, lin_b_w, lin_b_b, a_lin_w, a_lin_b,
                                          k_b, q_b, v_b, a_rel, m_rel, p_rel,
                                          bias_lin, wt_lin_a, wt_lin_b, wt_alin, b_kqv, dflag);
    k_prep_kqv_w<<<512, 384, 0, stream>>>(k_w, q_w, v_w, a_rel, m_rel, p_rel, wt_kqv, dflag);

    // -------- x inputs -> bf16 --------
    k_convb<<<(NAn * 64 + NBn * 32 + 255) / 256, 256, 0, stream>>>(x_a, x_b, x_a_bf, x_b_bf, dflag);

    // -------- CSR build, both directions --------
    hipMemsetAsync(deg_ab, 0, 2 * NAn * sizeof(int), stream);
    dim3 eg((NEe + 255) / 256, 2);
    k_hist<<<eg, 256, 0, stream>>>(edge_ab + NEe, edge_ba + NEe, deg_ab, deg_ba);
    int nblk = (NBn + 255) / 256; // 157
    k_scanA<<<dim3(nblk, 2), 256, 0, stream>>>(deg_ab, deg_ba, rowptr_ab, rowptr_ba,
                                               bsum_ab, bsum_ba, NBn);
    k_scanB<<<2, 256, 0, stream>>>(bsum_ab, bsum_ba, nblk);
    k_scanC<<<dim3(nblk, 2), 256, 0, stream>>>(rowptr_ab, rowptr_ba, bsum_ab, bsum_ba,
                                               cursor_ab, cursor_ba, NBn);
    k_scatter<<<eg, 256, 0, stream>>>(edge_ab, edge_ba, cursor_ab, cursor_ba, csr_ab, csr_ba);

    // -------- input linears + relu --------
    k_mm2<64, 2, 1><<<dim3(NAn / 64, 1), 256, 0, stream>>>(
        x_a_bf, x_a_bf, 64, wt_lin_a, wt_lin_a, bias_lin, bias_lin,
        xa_bf, xa_bf, 128, nullptr, nullptr, nullptr, 0, 0, dflag);
    k_mm2<32, 2, 1><<<dim3(NBn / 64, 1), 256, 0, stream>>>(
        x_b_bf, x_b_bf, 32, wt_lin_b, wt_lin_b, bias_lin + 128, bias_lin + 128,
        xb_bf, xb_bf, 128, nullptr, nullptr, nullptr, 0, 0, dflag);

    // -------- layers --------
    for (int l = 0; l < Ll; ++l) {
        int lt0 = l * 2 + 0, lt1 = l * 2 + 1;
        k_mm2<128, 6, 0><<<dim3(NAn / 64, 2), 256, 0, stream>>>(
            xa_bf, xb_bf, 128,
            wt_kqv + (size_t)lt0 * 384 * 128, wt_kqv + (size_t)lt1 * 384 * 128,
            b_kqv + (size_t)lt0 * 384, b_kqv + (size_t)lt1 * 384,
            kqv_a, kqv_b, 384, nullptr, nullptr, nullptr, 0, 0, dflag);
        int nblk0 = (NBn + 3) / 4;
        k_edge<<<nblk0 + (NAn + 3) / 4, 256, 0, stream>>>(
            kqv_a, kqv_b, rowptr_ab, csr_ab,
            kqv_b, kqv_a, rowptr_ba, csr_ba, nblk0);
        // a_lin + skip blend (in-place update of xa_bf/xb_bf)
        k_mm2<128, 2, 2><<<dim3(NAn / 64, 2), 256, 0, stream>>>(
            kqv_a + 256, kqv_b + 256, 384,
            wt_alin + (size_t)lt0 * 128 * 128, wt_alin + (size_t)lt1 * 128 * 128,
            bias_lin + 256 + (size_t)lt0 * 128, bias_lin + 256 + (size_t)lt1 * 128,
            xa_bf, xb_bf, 128, xa_bf, xb_bf, skip, lt0, lt1, dflag);
    }

    // -------- output --------
    k_out<<<(2 * NAn * Cc / 8 + 255) / 256, 256, 0, stream>>>(xa_bf, xb_bf, d_out, dflag);
}

// Round 9
// 301.487 us; speedup vs baseline: 2.4339x; 1.0214x over previous
//
#include <hip/hip_runtime.h>
#include <hip/hip_bf16.h>
#include <math.h>

#define NAn 40000
#define NBn 40000
#define NEe 250000
#define Cc 128
#define Hh 4
#define Ll 2
static constexpr float INV_SQRT_D = 0.17677669529663687f; // 1/sqrt(32)
static constexpr float LOG2E = 1.4426950408889634f;

typedef __hip_bfloat16 bf16;
typedef unsigned short u16;
typedef unsigned int u32;
typedef short s16x8 __attribute__((ext_vector_type(8)));
typedef float f32x4 __attribute__((ext_vector_type(4)));
typedef float f32x2 __attribute__((ext_vector_type(2)));
typedef __bf16 bf16x2 __attribute__((ext_vector_type(2)));

#if defined(__has_builtin)
#  if __has_builtin(__builtin_amdgcn_fdot2_f32_bf16)
#    define HAVE_DOT2 1
#  endif
#endif
#ifndef HAVE_DOT2
#  define HAVE_DOT2 0
#endif

__device__ __forceinline__ float bf2f(bf16 x) { return __bfloat162float(x); }
__device__ __forceinline__ float lo_bf(u32 w) { return __uint_as_float(w << 16); }
__device__ __forceinline__ float hi_bf(u32 w) { return __uint_as_float(w & 0xffff0000u); }
__device__ __forceinline__ float ldf(const void* p, size_t i, int isb) {
    return isb ? bf2f(((const bf16*)p)[i]) : ((const float*)p)[i];
}
__device__ __forceinline__ u16 f2bu(float v) {
    union { bf16 b; u16 u; } c; c.b = __float2bfloat16(v); return c.u;
}
__device__ __forceinline__ float gelu_f(float v) {
    return 0.5f * v * (1.f + erff(v * 0.70710678118f));
}
__device__ __forceinline__ bf16x2 as_b2(u32 w) {
    union { u32 u; bf16x2 v; } c; c.u = w; return c.v;
}

// ---------------- dtype detection ----------------
__global__ void k_detect(const u16* __restrict__ x, int n, int* __restrict__ flag) {
    __shared__ float smax[256];
    int tid = threadIdx.x;
    float m = 0.f;
    for (int i = tid; i < n; i += 256) {
        float v = fabsf(__uint_as_float(((u32)x[i]) << 16));
        if (v != v) v = 1e30f;
        m = fmaxf(m, v);
    }
    smax[tid] = m;
    __syncthreads();
    for (int s = 128; s > 0; s >>= 1) {
        if (tid < s) smax[tid] = fmaxf(smax[tid], smax[tid + s]);
        __syncthreads();
    }
    if (tid == 0) flag[0] = (smax[0] > 1e4f) ? 0 : 1;
}

// ---------------- merged x-input convert ----------------
__global__ void k_convb(const void* __restrict__ xa, const void* __restrict__ xb,
                        bf16* __restrict__ da, bf16* __restrict__ db,
                        const int* __restrict__ dflag) {
    int isb = dflag[0];
    int i = blockIdx.x * 256 + threadIdx.x;
    int na = NAn * 64;
    if (i < na) da[i] = isb ? ((const bf16*)xa)[i] : __float2bfloat16(((const float*)xa)[i]);
    else if (i < na + NBn * 32) {
        int j = i - na;
        db[j] = isb ? ((const bf16*)xb)[j] : __float2bfloat16(((const float*)xb)[j]);
    }
}

// ---------------- merged small weight prep (384 threads) + deg zeroing ----------------
// blocks [0,2): bias_lin[768]; [2,205): wt transposes; [205,209): kqv bias (layout [k|v|q])
// every thread additionally zeros one entry of deg[2*NAn] (replaces hipMemsetAsync)
__global__ void k_prep_small(const void* __restrict__ lin_a_w, const void* __restrict__ lin_a_b,
                             const void* __restrict__ lin_b_w, const void* __restrict__ lin_b_b,
                             const void* __restrict__ a_lin_w, const void* __restrict__ a_lin_b,
                             const void* __restrict__ k_b, const void* __restrict__ q_b,
                             const void* __restrict__ v_b, const void* __restrict__ a_rel,
                             const void* __restrict__ m_rel, const void* __restrict__ p_rel,
                             float* __restrict__ bias_lin, bf16* __restrict__ wt_lin_a,
                             bf16* __restrict__ wt_lin_b, bf16* __restrict__ wt_alin,
                             float* __restrict__ b_kqv, int* __restrict__ deg,
                             const int* __restrict__ dflag) {
    int isb = dflag[0];
    int b = blockIdx.x, t = threadIdx.x;
    int z = b * 384 + t;
    if (z < 2 * NAn) deg[z] = 0;
    if (b < 2) {
        int i = b * 384 + t;
        if (i < 768) {
            float v = (i < 128) ? ldf(lin_a_b, i, isb)
                    : (i < 256) ? ldf(lin_b_b, i - 128, isb)
                                : ldf(a_lin_b, i - 256, isb);
            bias_lin[i] = v;
        }
    } else if (b < 205) {
        int e = (b - 2) * 384 + t;
        if (e < 8192) {            // wt_lin_a [128][64]
            int n = e >> 6, k = e & 63;
            wt_lin_a[e] = __float2bfloat16(ldf(lin_a_w, (size_t)k * 128 + n, isb));
        } else if (e < 12288) {    // wt_lin_b [128][32]
            int r = e - 8192; int n = r >> 5, k = r & 31;
            wt_lin_b[r] = __float2bfloat16(ldf(lin_b_w, (size_t)k * 128 + n, isb));
        } else if (e < 77824) {    // wt_alin [4][128][128]
            int r = e - 12288; int s = r >> 14, rem = r & 16383;
            int n = rem >> 7, k = rem & 127;
            wt_alin[r] = __float2bfloat16(ldf(a_lin_w, (size_t)s * 16384 + (size_t)k * 128 + n, isb));
        }
    } else {                       // kqv bias, lt = b-205; layout [k|v|q]; k scaled by LOG2E
        int lt = b - 205, j = t;
        float out;
        if (j < 128) {
            int h = j >> 5, e = j & 31;
            float s = ldf(p_rel, lt * Hh + h, isb) * INV_SQRT_D * LOG2E;
            float sum = 0.f;
            size_t kb0 = (size_t)lt * 128 + h * 32;
            size_t ar0 = ((size_t)lt * Hh + h) * 1024 + e;
            #pragma unroll
            for (int d = 0; d < 32; ++d) sum += ldf(k_b, kb0 + d, isb) * ldf(a_rel, ar0 + d * 32, isb);
            out = sum * s;
        } else if (j < 256) {
            int jj = j - 128; int h = jj >> 5, e = jj & 31;
            float sum = 0.f;
            size_t vb0 = (size_t)lt * 128 + h * 32;
            size_t mr0 = ((size_t)lt * Hh + h) * 1024 + e;
            #pragma unroll
            for (int d = 0; d < 32; ++d) sum += ldf(v_b, vb0 + d, isb) * ldf(m_rel, mr0 + d * 32, isb);
            out = sum;
        } else {
            out = ldf(q_b, (size_t)lt * 128 + (j - 256), isb);
        }
        b_kqv[(size_t)lt * 384 + j] = out;
    }
}

// ---------------- fused KQV weight prep: Wt[lt][384][128] bf16, layout [k|v|q] ----------------
__global__ void k_prep_kqv_w(const void* __restrict__ k_w, const void* __restrict__ q_w,
                             const void* __restrict__ v_w, const void* __restrict__ a_rel,
                             const void* __restrict__ m_rel, const void* __restrict__ p_rel,
                             bf16* __restrict__ Wt, const int* __restrict__ dflag) {
    int isb = dflag[0];
    int b = blockIdx.x;          // lt*128 + c (c = K index)
    int lt = b >> 7, c = b & 127;
    int j = threadIdx.x;         // 0..383 (N index)
    float out;
    if (j < 128) {               // k' scaled by p_rel/sqrt(D)*log2(e)
        int h = j >> 5, e = j & 31;
        float s = ldf(p_rel, lt * Hh + h, isb) * INV_SQRT_D * LOG2E;
        float sum = 0.f;
        size_t kw0 = ((size_t)lt * 128 + c) * 128 + h * 32;
        size_t ar0 = ((size_t)lt * Hh + h) * 1024 + e;
        #pragma unroll
        for (int d = 0; d < 32; ++d) sum += ldf(k_w, kw0 + d, isb) * ldf(a_rel, ar0 + d * 32, isb);
        out = sum * s;
    } else if (j < 256) {        // v'
        int jj = j - 128; int h = jj >> 5, e = jj & 31;
        float sum = 0.f;
        size_t vw0 = ((size_t)lt * 128 + c) * 128 + h * 32;
        size_t mr0 = ((size_t)lt * Hh + h) * 1024 + e;
        #pragma unroll
        for (int d = 0; d < 32; ++d) sum += ldf(v_w, vw0 + d, isb) * ldf(m_rel, mr0 + d * 32, isb);
        out = sum;
    } else {                     // q
        out = ldf(q_w, ((size_t)lt * 128 + c) * 128 + (j - 256), isb);
    }
    Wt[((size_t)lt * 384 + j) * 128 + c] = __float2bfloat16(out);
}

// ---------------- CSR build (both directions per launch) ----------------
__global__ void k_hist(const int* __restrict__ d0, const int* __restrict__ d1,
                       int* __restrict__ deg0, int* __restrict__ deg1) {
    int i = blockIdx.x * 256 + threadIdx.x;
    if (i >= NEe) return;
    if (blockIdx.y == 0) atomicAdd(&deg0[d0[i]], 1);
    else                 atomicAdd(&deg1[d1[i]], 1);
}

__global__ void k_scanA(const int* __restrict__ deg0, const int* __restrict__ deg1,
                        int* __restrict__ ex0, int* __restrict__ ex1,
                        int* __restrict__ bs0, int* __restrict__ bs1, int n) {
    const int* deg = blockIdx.y ? deg1 : deg0;
    int* excl = blockIdx.y ? ex1 : ex0;
    int* bsum = blockIdx.y ? bs1 : bs0;
    __shared__ int buf[256];
    int tid = threadIdx.x;
    int i = blockIdx.x * 256 + tid;
    int v = (i < n) ? deg[i] : 0;
    buf[tid] = v;
    __syncthreads();
    for (int off = 1; off < 256; off <<= 1) {
        int u = (tid >= off) ? buf[tid - off] : 0;
        __syncthreads();
        buf[tid] += u;
        __syncthreads();
    }
    int incl = buf[tid];
    if (i < n) excl[i] = incl - v;
    if (tid == 255) bsum[blockIdx.x] = incl;
}

__global__ void k_scanB(int* __restrict__ bs0, int* __restrict__ bs1, int nb) {
    int* bsum = blockIdx.x ? bs1 : bs0;
    __shared__ int buf[256];
    int tid = threadIdx.x;
    int v = (tid < nb) ? bsum[tid] : 0;
    buf[tid] = v;
    __syncthreads();
    for (int off = 1; off < 256; off <<= 1) {
        int u = (tid >= off) ? buf[tid - off] : 0;
        __syncthreads();
        buf[tid] += u;
        __syncthreads();
    }
    if (tid < nb) bsum[tid] = buf[tid] - v;
}

__global__ void k_scanC(int* __restrict__ rp0, int* __restrict__ rp1,
                        const int* __restrict__ bs0, const int* __restrict__ bs1,
                        int* __restrict__ cur0, int* __restrict__ cur1, int n) {
    int* rowptr = blockIdx.y ? rp1 : rp0;
    const int* bsum = blockIdx.y ? bs1 : bs0;
    int* cursor = blockIdx.y ? cur1 : cur0;
    int i = blockIdx.x * 256 + threadIdx.x;
    if (i < n) {
        int v = rowptr[i] + bsum[i >> 8];
        rowptr[i] = v;
        cursor[i] = v;
    }
    if (i == 0) rowptr[n] = NEe;
}

__global__ void k_scatter(const int* __restrict__ e0, const int* __restrict__ e1,
                          int* __restrict__ cur0, int* __restrict__ cur1,
                          int* __restrict__ cs0, int* __restrict__ cs1) {
    int i = blockIdx.x * 256 + threadIdx.x;
    if (i >= NEe) return;
    const int* e = blockIdx.y ? e1 : e0;
    int* cursor = blockIdx.y ? cur1 : cur0;
    int* csr = blockIdx.y ? cs1 : cs0;
    int d = e[NEe + i];
    int p = atomicAdd(&cursor[d], 1);
    csr[p] = e[i];
}

// ---------------- MFMA GEMM (unchanged from R8) ----------------
// EPI: 0 = +bias ; 1 = relu ; 2 = skip blend s*(acc+bias)+(1-s)*oldx
template <int KK, int NSTEPS, int EPI>
__global__ __launch_bounds__(256) void k_mm2(const bf16* __restrict__ A0, const bf16* __restrict__ A1,
                                             int lda,
                                             const bf16* __restrict__ W0, const bf16* __restrict__ W1,
                                             const float* __restrict__ bias0, const float* __restrict__ bias1,
                                             bf16* __restrict__ out0, bf16* __restrict__ out1, int ldo,
                                             const bf16* __restrict__ old0, const bf16* __restrict__ old1,
                                             const void* __restrict__ skipp, int si0, int si1,
                                             const int* __restrict__ dflag) {
    constexpr int NK = KK / 32;
    int y = blockIdx.y;
    const bf16* A = y ? A1 : A0;
    const bf16* Wt = y ? W1 : W0;
    const float* bias = y ? bias1 : bias0;
    bf16* out = y ? out1 : out0;
    const bf16* oldx = y ? old1 : old0;
    int skip_idx = y ? si1 : si0;

    int tid = threadIdx.x;
    int w = tid >> 6, l = tid & 63;
    int r0 = blockIdx.x * 64 + (w & 1) * 32;
    int n0base = (w >> 1) * (NSTEPS * 32);
    int lr = l & 15, kb = l >> 4;

    s16x8 af[2][NK];
    #pragma unroll
    for (int mt = 0; mt < 2; ++mt)
        #pragma unroll
        for (int kf = 0; kf < NK; ++kf)
            af[mt][kf] = *(const s16x8*)(A + (size_t)(r0 + mt * 16 + lr) * lda + kf * 32 + kb * 8);

    s16x8 bfr[2][2][NK];
    #pragma unroll
    for (int nt = 0; nt < 2; ++nt)
        #pragma unroll
        for (int kf = 0; kf < NK; ++kf)
            bfr[0][nt][kf] = *(const s16x8*)(Wt + (size_t)(n0base + nt * 16 + lr) * KK + kf * 32 + kb * 8);

    float sg = 0.f;
    if (EPI == 2) {
        float sv = ldf(skipp, skip_idx, dflag[0]);
        sg = 1.f / (1.f + expf(-sv));
    }

    #pragma unroll
    for (int s = 0; s < NSTEPS; ++s) {
        int n0 = n0base + s * 32;
        if (s + 1 < NSTEPS) {
            #pragma unroll
            for (int nt = 0; nt < 2; ++nt)
                #pragma unroll
                for (int kf = 0; kf < NK; ++kf)
                    bfr[(s + 1) & 1][nt][kf] =
                        *(const s16x8*)(Wt + (size_t)(n0 + 32 + nt * 16 + lr) * KK + kf * 32 + kb * 8);
        }
        f32x4 acc[2][2] = {};
        #pragma unroll
        for (int kf = 0; kf < NK; ++kf)
            #pragma unroll
            for (int mt = 0; mt < 2; ++mt)
                #pragma unroll
                for (int nt = 0; nt < 2; ++nt)
                    acc[mt][nt] = __builtin_amdgcn_mfma_f32_16x16x32_bf16(
                        af[mt][kf], bfr[s & 1][nt][kf], acc[mt][nt], 0, 0, 0);
        #pragma unroll
        for (int mt = 0; mt < 2; ++mt)
            #pragma unroll
            for (int nt = 0; nt < 2; ++nt) {
                int col = n0 + nt * 16 + lr;
                float bv = bias[col];
                #pragma unroll
                for (int r = 0; r < 4; ++r) {
                    int row = r0 + mt * 16 + kb * 4 + r;
                    float o = acc[mt][nt][r] + bv;
                    if (EPI == 1) o = fmaxf(o, 0.f);
                    if (EPI == 2) o = sg * o + (1.f - sg) * bf2f(oldx[(size_t)row * 128 + col]);
                    out[(size_t)row * ldo + col] = __float2bfloat16(o);
                }
            }
    }
}

// ---------------- fused edge aggregation v4: 2 nodes/wave, reduce-scatter epilogue ----------------
// Block = 4 waves = 8 nodes. Within a node (32 lanes): eg = (lane&31)>>4 (2 edges in
// flight), hp = lane&15 (16B k/v slice). kqv layout [k|v|q]; k' pre-scaled by log2(e).
// Writes gelu(attn) into q-cols. Requires NAn % 8 == 0 (40000/8 = 5000 blocks/dir).
__global__ __launch_bounds__(256) void k_edge(const bf16* __restrict__ kv0, bf16* __restrict__ qm0,
                                              const int* __restrict__ rp0, const int* __restrict__ cs0,
                                              const bf16* __restrict__ kv1, bf16* __restrict__ qm1,
                                              const int* __restrict__ rp1, const int* __restrict__ cs1,
                                              int nblk0) {
    int dir = (blockIdx.x >= nblk0);
    int blk = dir ? (blockIdx.x - nblk0) : blockIdx.x;
    const bf16* kv = dir ? kv1 : kv0;
    bf16* qm = dir ? qm1 : qm0;
    const int* rowptr = dir ? rp1 : rp0;
    const int* csr = dir ? cs1 : cs0;

    int tid = threadIdx.x;
    int n = blk * 8 + (tid >> 5);       // node index (8 per block, 2 per wave)
    int l5 = tid & 31;
    int eg = l5 >> 4, hp = l5 & 15;
    bf16* qrow = qm + (size_t)n * 384 + 256;

    uint4 qv = *(const uint4*)(qrow + hp * 8);
#if HAVE_DOT2
    bf16x2 qb0 = as_b2(qv.x), qb1 = as_b2(qv.y), qb2 = as_b2(qv.z), qb3 = as_b2(qv.w);
#else
    float qf0 = lo_bf(qv.x), qf1 = hi_bf(qv.x), qf2 = lo_bf(qv.y), qf3 = hi_bf(qv.y);
    float qf4 = lo_bf(qv.z), qf5 = hi_bf(qv.z), qf6 = lo_bf(qv.w), qf7 = hi_bf(qv.w);
#endif

    float den = 0.f;
    f32x2 a01 = {0.f, 0.f}, a23 = {0.f, 0.f}, a45 = {0.f, 0.f}, a67 = {0.f, 0.f};
    int e0 = rowptr[n], e1 = rowptr[n + 1];
    int sidx_n = 0;
    {
        int ee = e0 + eg;
        if (ee < e1) sidx_n = csr[ee];
    }
    for (int e = e0; e < e1; e += 2) {
        int sidx = sidx_n;
        bool valid = (e + eg) < e1;
        int en = e + 2 + eg;
        if (en < e1) sidx_n = csr[en];     // prefetch next iteration's index
        const bf16* row = kv + (size_t)sidx * 384;
        uint4 kw = *(const uint4*)(row + hp * 8);
        uint4 vw = *(const uint4*)(row + 128 + hp * 8);
#if HAVE_DOT2
        float part = __builtin_amdgcn_fdot2_f32_bf16(as_b2(kw.x), qb0, 0.f, false);
        part = __builtin_amdgcn_fdot2_f32_bf16(as_b2(kw.y), qb1, part, false);
        part = __builtin_amdgcn_fdot2_f32_bf16(as_b2(kw.z), qb2, part, false);
        part = __builtin_amdgcn_fdot2_f32_bf16(as_b2(kw.w), qb3, part, false);
#else
        float part = qf0 * lo_bf(kw.x) + qf1 * hi_bf(kw.x)
                   + qf2 * lo_bf(kw.y) + qf3 * hi_bf(kw.y)
                   + qf4 * lo_bf(kw.z) + qf5 * hi_bf(kw.z)
                   + qf6 * lo_bf(kw.w) + qf7 * hi_bf(kw.w);
#endif
        part += __shfl_xor(part, 1);
        part += __shfl_xor(part, 2);
        float wgt = valid ? exp2f(part) : 0.f;
        den += wgt;
        f32x2 w2; w2[0] = wgt; w2[1] = wgt;
        f32x2 t;
        t[0] = lo_bf(vw.x); t[1] = hi_bf(vw.x); a01 += w2 * t;
        t[0] = lo_bf(vw.y); t[1] = hi_bf(vw.y); a23 += w2 * t;
        t[0] = lo_bf(vw.z); t[1] = hi_bf(vw.z); a45 += w2 * t;
        t[0] = lo_bf(vw.w); t[1] = hi_bf(vw.w); a67 += w2 * t;
    }
    // den all-reduce across the node's two e-groups
    den += __shfl_xor(den, 16);
    // reduce-scatter accumulators: eg=0 ends with pairs {0,1}, eg=1 with {2,3}
    f32x2 sA = eg ? a01 : a45;     // half I discard (partner needs it)
    f32x2 sB = eg ? a23 : a67;
    f32x2 rA, rB;
    rA[0] = __shfl_xor(sA[0], 16); rA[1] = __shfl_xor(sA[1], 16);
    rB[0] = __shfl_xor(sB[0], 16); rB[1] = __shfl_xor(sB[1], 16);
    f32x2 kA = eg ? a45 : a01; kA += rA;   // pair (2eg+0)
    f32x2 kB = eg ? a67 : a23; kB += rB;   // pair (2eg+1)
    float inv = 1.f / (den + 1e-16f);
    u32 p0 = (u32)f2bu(gelu_f(kA[0] * inv)) | ((u32)f2bu(gelu_f(kA[1] * inv)) << 16);
    u32 p1 = (u32)f2bu(gelu_f(kB[0] * inv)) | ((u32)f2bu(gelu_f(kB[1] * inv)) << 16);
    uint2 st; st.x = p0; st.y = p1;
    *(uint2*)(qrow + hp * 8 + 4 * eg) = st;   // cols hp*8 + 4*eg .. +3
}

// ---------------- final output (adaptive dtype), vectorized 8 elems/thread ----------------
__global__ void k_out(const bf16* __restrict__ xa, const bf16* __restrict__ xb,
                      void* __restrict__ out, const int* __restrict__ dflag) {
    int isb = dflag[0];
    int i = blockIdx.x * 256 + threadIdx.x;   // 8-elem group index
    int na8 = NAn * Cc / 8;
    if (i >= 2 * na8) return;
    const bf16* src = (i < na8) ? xa : xb;
    int j = (i < na8) ? i : i - na8;
    uint4 v = *(const uint4*)(src + (size_t)j * 8);
    if (isb) {
        ((uint4*)out)[i] = v;
    } else {
        float4 f0 = make_float4(lo_bf(v.x), hi_bf(v.x), lo_bf(v.y), hi_bf(v.y));
        float4 f1 = make_float4(lo_bf(v.z), hi_bf(v.z), lo_bf(v.w), hi_bf(v.w));
        ((float4*)out)[i * 2] = f0;
        ((float4*)out)[i * 2 + 1] = f1;
    }
}

extern "C" void kernel_launch(void* const* d_in, const int* in_sizes, int n_in,
                              void* d_out, int out_size, void* d_ws, size_t ws_size,
                              hipStream_t stream) {
    const void* x_a     = d_in[0];
    const void* x_b     = d_in[1];
    const int*  edge_ab = (const int*)d_in[2];
    const int*  edge_ba = (const int*)d_in[3];
    const void* lin_a_w = d_in[4];
    const void* lin_a_b = d_in[5];
    const void* lin_b_w = d_in[6];
    const void* lin_b_b = d_in[7];
    const void* k_w     = d_in[8];
    const void* k_b     = d_in[9];
    const void* q_w     = d_in[10];
    const void* q_b     = d_in[11];
    const void* v_w     = d_in[12];
    const void* v_b     = d_in[13];
    const void* a_rel   = d_in[14];
    const void* m_rel   = d_in[15];
    const void* p_rel   = d_in[16];
    const void* a_lin_w = d_in[17];
    const void* a_lin_b = d_in[18];
    const void* skip    = d_in[19];

    // -------- workspace layout --------
    char* p = (char*)d_ws;
    auto falloc = [&](size_t n) { float* r = (float*)p; p += n * sizeof(float); return r; };
    float* bias_lin = falloc(768);       // [lin_a_b | lin_b_b | a_lin_b(512)]
    float* b_kqv    = falloc(4 * 384);
    auto halloc = [&](size_t n) { bf16* r = (bf16*)p; p += n * sizeof(bf16); return r; };
    bf16* x_a_bf   = halloc((size_t)NAn * 64);
    bf16* x_b_bf   = halloc((size_t)NBn * 32);
    bf16* xa_bf    = halloc((size_t)NAn * Cc);
    bf16* xb_bf    = halloc((size_t)NBn * Cc);
    bf16* kqv_a    = halloc((size_t)NAn * 384);
    bf16* kqv_b    = halloc((size_t)NBn * 384);
    bf16* wt_lin_a = halloc(128 * 64);
    bf16* wt_lin_b = halloc(128 * 32);
    bf16* wt_kqv   = halloc(4 * 384 * 128);
    bf16* wt_alin  = halloc(4 * 128 * 128);
    auto ialloc = [&](size_t n) { int* r = (int*)p; p += n * sizeof(int); return r; };
    int* dflag     = ialloc(4);
    int* rowptr_ab = ialloc(NBn + 1);
    int* rowptr_ba = ialloc(NAn + 1);
    int* deg_ab    = ialloc(NBn);       // deg_ab/deg_ba adjacent -> zeroed by k_prep_small
    int* deg_ba    = ialloc(NAn);
    int* cursor_ab = ialloc(NBn);
    int* cursor_ba = ialloc(NAn);
    int* bsum_ab   = ialloc(256);
    int* bsum_ba   = ialloc(256);
    int* csr_ab    = ialloc(NEe);
    int* csr_ba    = ialloc(NEe);

    // -------- dtype detection --------
    k_detect<<<1, 256, 0, stream>>>((const u16*)x_a, 8192, dflag);

    // -------- weight prep (2 launches; prep_small also zeros deg) --------
    k_prep_small<<<209, 384, 0, stream>>>(lin_a_w, lin_a_b, lin_b_w, lin_b_b, a_lin_w, a_lin_b,
                                          k_b, q_b, v_b, a_rel, m_rel, p_rel,
                                          bias_lin, wt_lin_a, wt_lin_b, wt_alin, b_kqv,
                                          deg_ab, dflag);
    k_prep_kqv_w<<<512, 384, 0, stream>>>(k_w, q_w, v_w, a_rel, m_rel, p_rel, wt_kqv, dflag);

    // -------- x inputs -> bf16 --------
    k_convb<<<(NAn * 64 + NBn * 32 + 255) / 256, 256, 0, stream>>>(x_a, x_b, x_a_bf, x_b_bf, dflag);

    // -------- CSR build, both directions --------
    dim3 eg((NEe + 255) / 256, 2);
    k_hist<<<eg, 256, 0, stream>>>(edge_ab + NEe, edge_ba + NEe, deg_ab, deg_ba);
    int nblk = (NBn + 255) / 256; // 157
    k_scanA<<<dim3(nblk, 2), 256, 0, stream>>>(deg_ab, deg_ba, rowptr_ab, rowptr_ba,
                                               bsum_ab, bsum_ba, NBn);
    k_scanB<<<2, 256, 0, stream>>>(bsum_ab, bsum_ba, nblk);
    k_scanC<<<dim3(nblk, 2), 256, 0, stream>>>(rowptr_ab, rowptr_ba, bsum_ab, bsum_ba,
                                               cursor_ab, cursor_ba, NBn);
    k_scatter<<<eg, 256, 0, stream>>>(edge_ab, edge_ba, cursor_ab, cursor_ba, csr_ab, csr_ba);

    // -------- input linears + relu --------
    k_mm2<64, 2, 1><<<dim3(NAn / 64, 1), 256, 0, stream>>>(
        x_a_bf, x_a_bf, 64, wt_lin_a, wt_lin_a, bias_lin, bias_lin,
        xa_bf, xa_bf, 128, nullptr, nullptr, nullptr, 0, 0, dflag);
    k_mm2<32, 2, 1><<<dim3(NBn / 64, 1), 256, 0, stream>>>(
        x_b_bf, x_b_bf, 32, wt_lin_b, wt_lin_b, bias_lin + 128, bias_lin + 128,
        xb_bf, xb_bf, 128, nullptr, nullptr, nullptr, 0, 0, dflag);

    // -------- layers --------
    for (int l = 0; l < Ll; ++l) {
        int lt0 = l * 2 + 0, lt1 = l * 2 + 1;
        k_mm2<128, 6, 0><<<dim3(NAn / 64, 2), 256, 0, stream>>>(
            xa_bf, xb_bf, 128,
            wt_kqv + (size_t)lt0 * 384 * 128, wt_kqv + (size_t)lt1 * 384 * 128,
            b_kqv + (size_t)lt0 * 384, b_kqv + (size_t)lt1 * 384,
            kqv_a, kqv_b, 384, nullptr, nullptr, nullptr, 0, 0, dflag);
        int nblk0 = NBn / 8; // 5000 blocks per direction, 8 nodes/block
        k_edge<<<nblk0 + NAn / 8, 256, 0, stream>>>(
            kqv_a, kqv_b, rowptr_ab, csr_ab,
            kqv_b, kqv_a, rowptr_ba, csr_ba, nblk0);
        // a_lin + skip blend (in-place update of xa_bf/xb_bf)
        k_mm2<128, 2, 2><<<dim3(NAn / 64, 2), 256, 0, stream>>>(
            kqv_a + 256, kqv_b + 256, 384,
            wt_alin + (size_t)lt0 * 128 * 128, wt_alin + (size_t)lt1 * 128 * 128,
            bias_lin + 256 + (size_t)lt0 * 128, bias_lin + 256 + (size_t)lt1 * 128,
            xa_bf, xb_bf, 128, xa_bf, xb_bf, skip, lt0, lt1, dflag);
    }

    // -------- output --------
    k_out<<<(2 * NAn * Cc / 8 + 255) / 256, 256, 0, stream>>>(xa_bf, xb_bf, d_out, dflag);
}